// Round 8
// baseline (439.269 us; speedup 1.0000x reference)
//
#include <hip/hip_runtime.h>

// ---------------------------------------------------------------------------
// GQA forward, fp32 I/O, bf16 MFMA compute.
// B=2 S=2048 D=2048 HQ=32 HKV=8 HD=64.
// cvt4 (w/ head-col permutation for Q,K) -> QKV GEMM (256x192 relaxed
// 3-barrier schedule) -> V transpose -> flash attn (ROUND-12: pair-fused
// 2-tile iterations, XOR-swizzled LDS, setprio) -> cvt(Wo) ->
// O GEMM (256x128 4-phase, reverted to round-6 known-good).
// ---------------------------------------------------------------------------

typedef __bf16 bf16x8 __attribute__((ext_vector_type(8)));
typedef __bf16 bf16x4 __attribute__((ext_vector_type(4)));
typedef float f32x4 __attribute__((ext_vector_type(4)));

__device__ inline f32x4 mfma16(bf16x8 a, bf16x8 b, f32x4 c) {
    return __builtin_amdgcn_mfma_f32_16x16x32_bf16(a, b, c, 0, 0, 0);
}

__device__ inline void gld16(const __bf16* g, __bf16* l) {
    __builtin_amdgcn_global_load_lds(
        (const __attribute__((address_space(1))) void*)g,
        (__attribute__((address_space(3))) void*)l, 16, 0, 0);
}

__device__ inline bf16x4 pk4(float a, float b, float c, float d) {
    bf16x4 r; r[0] = (__bf16)a; r[1] = (__bf16)b; r[2] = (__bf16)c; r[3] = (__bf16)d;
    return r;
}

// 1/sqrt(64) * log2(e): attn computes exp2(score) = exp(qk/8)
#define SCALE_Q 0.18033688011112042f
#define L2IF    0.4152410118609203f    // log2(10000)/32
#define INV2PI  0.15915494309189535f

// Head-column permutation: natural within-head d -> storage slot.
__device__ inline int permrow(int n) {
    int nod = n & 63;
    int hj = ((nod >> 5) & 1) | (((nod >> 4) & 1) << 1);
    return (n & ~63) | (hj << 4) | (nod & 15);
}

// ---------------- fused fp32->bf16 for x, Wq, Wk, Wv ------------------------
__global__ void cvt4_kernel(const float* __restrict__ x,  const float* __restrict__ wq,
                            const float* __restrict__ wk, const float* __restrict__ wv,
                            __bf16* __restrict__ xb, __bf16* __restrict__ wqkvb)
{
    int i = blockIdx.x * blockDim.x + threadIdx.x;
    const float* src; __bf16* dst;
    if (i < 2097152)      { src = x  + (size_t)i * 4;  dst = xb + (size_t)i * 4; }
    else if (i < 3145728) {
        int j = i - 2097152; int n = j >> 9; int off = (j & 511) * 4;
        src = wq + (size_t)j * 4;
        dst = wqkvb + (size_t)permrow(n) * 2048 + off;
    }
    else if (i < 3407872) {
        int j = i - 3145728; int n = j >> 9; int off = (j & 511) * 4;
        src = wk + (size_t)j * 4;
        dst = wqkvb + 4194304 + (size_t)permrow(n) * 2048 + off;
    }
    else                  { int j = i - 3407872; src = wv + (size_t)j * 4; dst = wqkvb + 5242880 + (size_t)j * 4; }
    float4 f = *(const float4*)src;
    *(bf16x4*)dst = pk4(f.x, f.y, f.z, f.w);
}

__global__ void cvt_kernel(const float* __restrict__ in, __bf16* __restrict__ out, int n4)
{
    int i = blockIdx.x * blockDim.x + threadIdx.x;
    if (i >= n4) return;
    float4 f = ((const float4*)in)[i];
    ((bf16x4*)out)[i] = pk4(f.x, f.y, f.z, f.w);
}

// ---------------- 256x192 GEMM (QKV): 3-barrier relaxed schedule ------------
__global__ __launch_bounds__(512, 2) void gemm_qkv(
    const __bf16* __restrict__ A, const __bf16* __restrict__ Bw,
    __bf16* __restrict__ C, int M, int N, int K)
{
    __shared__ __bf16 LA[2][16384];   // 256 x 64
    __shared__ __bf16 LB[2][12288];   // 192 x 64
    const int tid  = threadIdx.x;
    const int lane = tid & 63;
    const int w    = tid >> 6;
    const int lm   = lane & 15;
    const int quad = lane >> 4;
    const int wr   = w >> 1;     // 0..3 (M)
    const int wc   = w & 1;      // 0..1 (N)

    int bx, by;
    {
        int id  = blockIdx.x + gridDim.x * blockIdx.y;   // 256 wgs
        int swz = (id & 7) * 32 + (id >> 3);
        by = swz >> 4;
        bx = swz & 15;
    }
    const int m0 = by * 256;
    const int n0 = bx * 192;
    const int NT = K >> 6;

    const int srow = tid >> 3;
    const int scol = ((tid & 7) ^ (srow & 7)) * 8;   // pre-swizzled source col
    const int ldst = tid * 8;                        // linear LDS dest
    const __bf16* ga = A  + (size_t)(m0 + srow) * K + scol;
    const __bf16* gb = Bw + (size_t)(n0 + srow) * K + scol;

    auto STA = [&](int bf, int r, int u) {
        gld16(ga + (size_t)r * K + u * 64, &LA[bf][r * 64 + ldst]);
    };
    auto STB = [&](int bf, int r, int u) {
        gld16(gb + (size_t)r * K + u * 64, &LB[bf][r * 64 + ldst]);
    };

    f32x4 acc[4][6];
    #pragma unroll
    for (int i = 0; i < 4; ++i)
        #pragma unroll
        for (int j = 0; j < 6; ++j)
            acc[i][j] = (f32x4){0.f, 0.f, 0.f, 0.f};

    const int axo = (wr * 64 + lm) * 64;
    const int bxo = (wc * 96 + lm) * 64;
    const int ks0 = ((quad * 8)      ^ ((lm & 7) * 8));
    const int ks1 = ((32 + quad * 8) ^ ((lm & 7) * 8));

    STA(0, 0, 0); STA(0, 64, 0); STA(0, 128, 0); STA(0, 192, 0);
    STB(0, 0, 0); STB(0, 64, 0); STB(0, 128, 0);
    STA(1, 0, 1); STA(1, 64, 1); STA(1, 128, 1); STA(1, 192, 1);
    STB(1, 0, 1); STB(1, 64, 1); STB(1, 128, 1);
    asm volatile("s_waitcnt vmcnt(7)" ::: "memory");
    __builtin_amdgcn_s_barrier();
    asm volatile("" ::: "memory");

    bf16x8 A01[2][2], A23[2][2], B1[3][2], B2[3][2];
    for (int t = 0; t < NT; ++t) {
        const int b = t & 1;
        const __bf16* la = LA[b];
        const __bf16* lb = LB[b];
        #pragma unroll
        for (int mi = 0; mi < 2; ++mi) {
            A01[mi][0] = *(const bf16x8*)(la + axo + mi * 1024 + ks0);
            A01[mi][1] = *(const bf16x8*)(la + axo + mi * 1024 + ks1);
        }
        #pragma unroll
        for (int ni = 0; ni < 3; ++ni) {
            B1[ni][0] = *(const bf16x8*)(lb + bxo + ni * 1024 + ks0);
            B1[ni][1] = *(const bf16x8*)(lb + bxo + ni * 1024 + ks1);
        }
        #pragma unroll
        for (int ni = 0; ni < 3; ++ni) {
            B2[ni][0] = *(const bf16x8*)(lb + bxo + (ni + 3) * 1024 + ks0);
            B2[ni][1] = *(const bf16x8*)(lb + bxo + (ni + 3) * 1024 + ks1);
        }
        #pragma unroll
        for (int mi = 0; mi < 2; ++mi) {
            A23[mi][0] = *(const bf16x8*)(la + axo + (mi + 2) * 1024 + ks0);
            A23[mi][1] = *(const bf16x8*)(la + axo + (mi + 2) * 1024 + ks1);
        }
        __builtin_amdgcn_s_setprio(1);
        #pragma unroll
        for (int mi = 0; mi < 2; ++mi)
            #pragma unroll
            for (int ni = 0; ni < 3; ++ni) {
                acc[mi][ni] = mfma16(A01[mi][0], B1[ni][0], acc[mi][ni]);
                acc[mi][ni] = mfma16(A01[mi][1], B1[ni][1], acc[mi][ni]);
            }
        #pragma unroll
        for (int mi = 0; mi < 2; ++mi)
            #pragma unroll
            for (int ni = 0; ni < 3; ++ni) {
                acc[mi][ni + 3] = mfma16(A01[mi][0], B2[ni][0], acc[mi][ni + 3]);
                acc[mi][ni + 3] = mfma16(A01[mi][1], B2[ni][1], acc[mi][ni + 3]);
            }
        __builtin_amdgcn_s_setprio(0);
        asm volatile("s_waitcnt lgkmcnt(0)" ::: "memory");
        __builtin_amdgcn_s_barrier();
        asm volatile("" ::: "memory");
        if (t + 2 < NT) { STB(b, 0, t + 2); STB(b, 64, t + 2); STB(b, 128, t + 2); }
        __builtin_amdgcn_s_setprio(1);
        #pragma unroll
        for (int mi = 0; mi < 2; ++mi)
            #pragma unroll
            for (int ni = 0; ni < 3; ++ni) {
                acc[mi + 2][ni] = mfma16(A23[mi][0], B1[ni][0], acc[mi + 2][ni]);
                acc[mi + 2][ni] = mfma16(A23[mi][1], B1[ni][1], acc[mi + 2][ni]);
            }
        __builtin_amdgcn_s_setprio(0);
        __builtin_amdgcn_s_barrier();
        asm volatile("" ::: "memory");
        if (t + 2 < NT) {
            STA(b, 0, t + 2); STA(b, 64, t + 2);
            STA(b, 128, t + 2); STA(b, 192, t + 2);
        }
        __builtin_amdgcn_s_setprio(1);
        #pragma unroll
        for (int mi = 0; mi < 2; ++mi)
            #pragma unroll
            for (int ni = 0; ni < 3; ++ni) {
                acc[mi + 2][ni + 3] = mfma16(A23[mi][0], B2[ni][0], acc[mi + 2][ni + 3]);
                acc[mi + 2][ni + 3] = mfma16(A23[mi][1], B2[ni][1], acc[mi + 2][ni + 3]);
            }
        __builtin_amdgcn_s_setprio(0);
        if (t < NT - 2) asm volatile("s_waitcnt vmcnt(7)" ::: "memory");
        else            asm volatile("s_waitcnt vmcnt(0)" ::: "memory");
        __builtin_amdgcn_s_barrier();
        asm volatile("" ::: "memory");
    }

    // RoPE on permuted pairs: pair = (j even, j+1), freq idx = (hj>>1)*16+lm.
    {
        float invr[2];
        invr[0] = exp2f(-(float)lm        * L2IF) * INV2PI;
        invr[1] = exp2f(-(float)(16 + lm) * L2IF) * INV2PI;
        #pragma unroll
        for (int jp = 0; jp < 3; ++jp) {
            const int jlo = jp * 2;
            const int pcb = n0 + wc * 96 + jlo * 16;
            if (pcb >= 2560) continue;                 // V: no rope (wave-uniform)
            const int hj = (pcb >> 4) & 3;             // even
            const float fr = invr[hj >> 1];
            #pragma unroll
            for (int i = 0; i < 4; ++i)
                #pragma unroll
                for (int r = 0; r < 4; ++r) {
                    float tt = (float)((m0 + wr * 64 + i * 16 + quad * 4 + r) & 2047);
                    float aR = tt * fr;
                    aR -= floorf(aR);                  // revolutions
                    float cs = __builtin_amdgcn_cosf(aR);
                    float sn = __builtin_amdgcn_sinf(aR);
                    float x1 = acc[i][jlo][r], x2 = acc[i][jlo + 1][r];
                    acc[i][jlo][r]     = x1 * cs - x2 * sn;
                    acc[i][jlo + 1][r] = x2 * cs + x1 * sn;
                }
        }
    }

    // C-write: un-permute Q/K cols, scale Q.
    #pragma unroll
    for (int j = 0; j < 6; ++j) {
        const int pcb = n0 + wc * 96 + j * 16;
        int colb; float sc;
        if (pcb < 2560) {
            const int hj = (pcb >> 4) & 3;
            colb = (pcb & ~63) | ((hj & 1) << 5) | ((hj >> 1) << 4);
            sc = (pcb < 2048) ? SCALE_Q : 1.0f;
        } else { colb = pcb; sc = 1.0f; }
        #pragma unroll
        for (int i = 0; i < 4; ++i)
            #pragma unroll
            for (int r = 0; r < 4; ++r) {
                int row = m0 + wr * 64 + i * 16 + quad * 4 + r;
                C[(size_t)row * N + colb + lm] = (__bf16)(acc[i][j][r] * sc);
            }
    }
}

// ---------------- 256x128 4-phase GEMM (O proj): C fp32 (round-6 version) ---
__global__ __launch_bounds__(512, 2) void gemm_o(
    const __bf16* __restrict__ A, const __bf16* __restrict__ Bw,
    float* __restrict__ C, int M, int N, int K)
{
    __shared__ __bf16 LA[2][16384];   // 256x64
    __shared__ __bf16 LB[2][8192];    // 128x64
    const int tid  = threadIdx.x;
    const int lane = tid & 63;
    const int w    = tid >> 6;
    const int lm   = lane & 15;
    const int quad = lane >> 4;
    const int wr   = w >> 1;     // 0..3
    const int wc   = w & 1;      // 0..1

    int bx, by;
    {
        int id  = blockIdx.x + gridDim.x * blockIdx.y;   // 256 wgs
        int swz = (id & 7) * 32 + (id >> 3);
        by = swz >> 4;
        bx = swz & 15;
    }
    const int m0 = by * 256;
    const int n0 = bx * 128;
    const int NT = K >> 6;

    const int srow = tid >> 3;
    const int scol = ((tid & 7) ^ (srow & 7)) * 8;
    const int ldst = tid * 8;
    const __bf16* ga = A  + (size_t)(m0 + srow) * K + scol;
    const __bf16* gb = Bw + (size_t)(n0 + srow) * K + scol;

    auto STA = [&](int bf, int r, int u) {
        gld16(ga + (size_t)r * K + u * 64, &LA[bf][r * 64 + ldst]);
    };
    auto STB = [&](int bf, int r, int u) {
        gld16(gb + (size_t)r * K + u * 64, &LB[bf][r * 64 + ldst]);
    };

    f32x4 acc[4][4];
    #pragma unroll
    for (int i = 0; i < 4; ++i)
        #pragma unroll
        for (int j = 0; j < 4; ++j)
            acc[i][j] = (f32x4){0.f, 0.f, 0.f, 0.f};

    const int axo = (wr * 64 + lm) * 64;
    const int bxo = (wc * 64 + lm) * 64;
    const int ks0 = ((quad * 8)      ^ ((lm & 7) * 8));
    const int ks1 = ((32 + quad * 8) ^ ((lm & 7) * 8));

    STA(0, 0, 0); STA(0, 64, 0); STA(0, 128, 0); STA(0, 192, 0);
    STB(0, 0, 0); STB(0, 64, 0);
    STA(1, 0, 1); STA(1, 64, 1); STA(1, 128, 1); STA(1, 192, 1);
    STB(1, 0, 1); STB(1, 64, 1);
    asm volatile("s_waitcnt vmcnt(6)" ::: "memory");
    __builtin_amdgcn_s_barrier();
    asm volatile("" ::: "memory");

    bf16x8 Af[4][2], Bf[4][2];
    for (int t = 0; t < NT; ++t) {
        const int b = t & 1;
        const __bf16* la = LA[b];
        const __bf16* lb = LB[b];
        // ---- P1: read Af m0-1, Bf n0-1; MFMA (m01, n01)
        #pragma unroll
        for (int mi = 0; mi < 2; ++mi) {
            Af[mi][0] = *(const bf16x8*)(la + axo + mi * 1024 + ks0);
            Af[mi][1] = *(const bf16x8*)(la + axo + mi * 1024 + ks1);
        }
        #pragma unroll
        for (int ni = 0; ni < 2; ++ni) {
            Bf[ni][0] = *(const bf16x8*)(lb + bxo + ni * 1024 + ks0);
            Bf[ni][1] = *(const bf16x8*)(lb + bxo + ni * 1024 + ks1);
        }
        __builtin_amdgcn_s_barrier();
        asm volatile("s_waitcnt lgkmcnt(0)" ::: "memory");
        __builtin_amdgcn_s_setprio(1);
        #pragma unroll
        for (int mi = 0; mi < 2; ++mi)
            #pragma unroll
            for (int ni = 0; ni < 2; ++ni) {
                acc[mi][ni] = mfma16(Af[mi][0], Bf[ni][0], acc[mi][ni]);
                acc[mi][ni] = mfma16(Af[mi][1], Bf[ni][1], acc[mi][ni]);
            }
        __builtin_amdgcn_s_setprio(0);
        __builtin_amdgcn_s_barrier();
        // ---- P2: read Bf n2-3; MFMA (m01, n23)
        #pragma unroll
        for (int ni = 2; ni < 4; ++ni) {
            Bf[ni][0] = *(const bf16x8*)(lb + bxo + ni * 1024 + ks0);
            Bf[ni][1] = *(const bf16x8*)(lb + bxo + ni * 1024 + ks1);
        }
        __builtin_amdgcn_s_barrier();
        asm volatile("s_waitcnt lgkmcnt(0)" ::: "memory");
        __builtin_amdgcn_s_setprio(1);
        #pragma unroll
        for (int mi = 0; mi < 2; ++mi)
            #pragma unroll
            for (int ni = 2; ni < 4; ++ni) {
                acc[mi][ni] = mfma16(Af[mi][0], Bf[ni][0], acc[mi][ni]);
                acc[mi][ni] = mfma16(Af[mi][1], Bf[ni][1], acc[mi][ni]);
            }
        __builtin_amdgcn_s_setprio(0);
        __builtin_amdgcn_s_barrier();
        // ---- P3: read Af m2-3; stage B(t+2); MFMA (m23, n01)
        #pragma unroll
        for (int mi = 2; mi < 4; ++mi) {
            Af[mi][0] = *(const bf16x8*)(la + axo + mi * 1024 + ks0);
            Af[mi][1] = *(const bf16x8*)(la + axo + mi * 1024 + ks1);
        }
        if (t + 2 < NT) { STB(b, 0, t + 2); STB(b, 64, t + 2); }
        __builtin_amdgcn_s_barrier();
        asm volatile("s_waitcnt lgkmcnt(0)" ::: "memory");
        __builtin_amdgcn_s_setprio(1);
        #pragma unroll
        for (int mi = 2; mi < 4; ++mi)
            #pragma unroll
            for (int ni = 0; ni < 2; ++ni) {
                acc[mi][ni] = mfma16(Af[mi][0], Bf[ni][0], acc[mi][ni]);
                acc[mi][ni] = mfma16(Af[mi][1], Bf[ni][1], acc[mi][ni]);
            }
        __builtin_amdgcn_s_setprio(0);
        __builtin_amdgcn_s_barrier();
        // ---- P4: stage A(t+2); MFMA (m23, n23); counted vmcnt
        if (t + 2 < NT) {
            STA(b, 0, t + 2); STA(b, 64, t + 2);
            STA(b, 128, t + 2); STA(b, 192, t + 2);
        }
        __builtin_amdgcn_s_setprio(1);
        #pragma unroll
        for (int mi = 2; mi < 4; ++mi)
            #pragma unroll
            for (int ni = 2; ni < 4; ++ni) {
                acc[mi][ni] = mfma16(Af[mi][0], Bf[ni][0], acc[mi][ni]);
                acc[mi][ni] = mfma16(Af[mi][1], Bf[ni][1], acc[mi][ni]);
            }
        __builtin_amdgcn_s_setprio(0);
        if (t < NT - 2) asm volatile("s_waitcnt vmcnt(6)" ::: "memory");
        else            asm volatile("s_waitcnt vmcnt(0)" ::: "memory");
        __builtin_amdgcn_s_barrier();
        asm volatile("" ::: "memory");
    }

    #pragma unroll
    for (int i = 0; i < 4; ++i)
        #pragma unroll
        for (int j = 0; j < 4; ++j)
            #pragma unroll
            for (int r = 0; r < 4; ++r) {
                int row = m0 + wr * 64 + i * 16 + quad * 4 + r;
                int col = n0 + wc * 64 + j * 16 + lm;
                C[(size_t)row * N + col] = acc[i][j][r];
            }
}

// ---------------- V transpose: [4096 tok][512 d] (stride 3072) -> [512][4096]
__global__ __launch_bounds__(256) void transpose_kernel(
    const __bf16* __restrict__ in, __bf16* __restrict__ out, int rowstride)
{
    __shared__ __bf16 T[64][72];
    const int t0 = blockIdx.x * 64;
    const int d0 = blockIdx.y * 64;
    const int r = threadIdx.x >> 2, c = (threadIdx.x & 3) * 16;
    *(int4*)&T[r][c]     = *(const int4*)(in + (size_t)(t0 + r) * rowstride + d0 + c);
    *(int4*)&T[r][c + 8] = *(const int4*)(in + (size_t)(t0 + r) * rowstride + d0 + c + 8);
    __syncthreads();
    bf16x8 o0, o1;
    #pragma unroll
    for (int i = 0; i < 8; ++i) { o0[i] = T[c + i][r]; o1[i] = T[c + 8 + i][r]; }
    *(bf16x8*)(out + (size_t)(d0 + r) * 4096 + t0 + c)     = o0;
    *(bf16x8*)(out + (size_t)(d0 + r) * 4096 + t0 + c + 8) = o1;
}

// ---------------- Flash attention (ROUND-12: pair-fused 2-tile iters) -------
#define RS  64
#define PKS 64

__device__ inline void attn_tile(
    const bf16x8 (&qf)[2], f32x4 (&oacc)[4], float& l,
    int qbase, int k0, int w, int lm, int quad,
    const __bf16* Ks, const __bf16* Vs, __bf16* Ptw)
{
    const int kb0 = (quad ^ (lm & 7)) * 8;
    const int kb1 = ((quad + 4) ^ (lm & 7)) * 8;
    f32x4 st[4];
    #pragma unroll
    for (int n = 0; n < 4; ++n)
        st[n] = (f32x4){0.f, 0.f, 0.f, 0.f};

    __builtin_amdgcn_s_setprio(1);
    #pragma unroll
    for (int n = 0; n < 4; ++n) {
        bf16x8 kf0 = *(const bf16x8*)&Ks[(n * 16 + lm) * RS + kb0];
        bf16x8 kf1 = *(const bf16x8*)&Ks[(n * 16 + lm) * RS + kb1];
        st[n] = mfma16(kf0, qf[0], st[n]);
        st[n] = mfma16(kf1, qf[1], st[n]);
    }
    __builtin_amdgcn_s_setprio(0);

    const int qi = qbase + w * 16 + lm;
    const bool any_mask = (k0 + 63 > qbase + w * 16);
    #pragma unroll
    for (int n = 0; n < 4; ++n) {
        const int kv0 = k0 + n * 16 + quad * 4;
        float e0, e1, e2, e3;
        if (any_mask) {
            e0 = (kv0     > qi) ? 0.f : __builtin_amdgcn_exp2f(st[n][0]);
            e1 = (kv0 + 1 > qi) ? 0.f : __builtin_amdgcn_exp2f(st[n][1]);
            e2 = (kv0 + 2 > qi) ? 0.f : __builtin_amdgcn_exp2f(st[n][2]);
            e3 = (kv0 + 3 > qi) ? 0.f : __builtin_amdgcn_exp2f(st[n][3]);
        } else {
            e0 = __builtin_amdgcn_exp2f(st[n][0]); e1 = __builtin_amdgcn_exp2f(st[n][1]);
            e2 = __builtin_amdgcn_exp2f(st[n][2]); e3 = __builtin_amdgcn_exp2f(st[n][3]);
        }
        l += (e0 + e1) + (e2 + e3);
        *(bf16x4*)&Ptw[lm * PKS + ((n * 4 + quad) ^ ((lm & 7) << 1)) * 4] =
            pk4(e0, e1, e2, e3);
    }

    bf16x8 pf0 = *(const bf16x8*)&Ptw[lm * PKS + kb0];
    bf16x8 pf1 = *(const bf16x8*)&Ptw[lm * PKS + kb1];
    __builtin_amdgcn_s_setprio(1);
    #pragma unroll
    for (int dt = 0; dt < 4; ++dt) {
        bf16x8 vf0 = *(const bf16x8*)&Vs[(dt * 16 + lm) * RS + kb0];
        bf16x8 vf1 = *(const bf16x8*)&Vs[(dt * 16 + lm) * RS + kb1];
        oacc[dt] = mfma16(vf0, pf0, oacc[dt]);
        oacc[dt] = mfma16(vf1, pf1, oacc[dt]);
    }
    __builtin_amdgcn_s_setprio(0);
}

__device__ inline void attn_tile2(
    const bf16x8 (&qfA)[2], const bf16x8 (&qfB)[2],
    f32x4 (&oA)[4], f32x4 (&oB)[4], float& lA, float& lB,
    int qbA, int k0, int w, int lm, int quad,
    const __bf16* Ks, const __bf16* Vs, __bf16* PtA, __bf16* PtB)
{
    const int kb0 = (quad ^ (lm & 7)) * 8;
    const int kb1 = ((quad + 4) ^ (lm & 7)) * 8;
    f32x4 stA[4], stB[4];
    #pragma unroll
    for (int n = 0; n < 4; ++n) {
        stA[n] = (f32x4){0.f, 0.f, 0.f, 0.f};
        stB[n] = (f32x4){0.f, 0.f, 0.f, 0.f};
    }

    __builtin_amdgcn_s_setprio(1);
    #pragma unroll
    for (int n = 0; n < 4; ++n) {
        bf16x8 kf0 = *(const bf16x8*)&Ks[(n * 16 + lm) * RS + kb0];
        bf16x8 kf1 = *(const bf16x8*)&Ks[(n * 16 + lm) * RS + kb1];
        stB[n] = mfma16(kf0, qfB[0], stB[n]);
        stB[n] = mfma16(kf1, qfB[1], stB[n]);
        stA[n] = mfma16(kf0, qfA[0], stA[n]);
        stA[n] = mfma16(kf1, qfA[1], stA[n]);
    }
    __builtin_amdgcn_s_setprio(0);

    #pragma unroll
    for (int n = 0; n < 4; ++n) {
        float e0 = __builtin_amdgcn_exp2f(stB[n][0]);
        float e1 = __builtin_amdgcn_exp2f(stB[n][1]);
        float e2 = __builtin_amdgcn_exp2f(stB[n][2]);
        float e3 = __builtin_amdgcn_exp2f(stB[n][3]);
        lB += (e0 + e1) + (e2 + e3);
        *(bf16x4*)&PtB[lm * PKS + ((n * 4 + quad) ^ ((lm & 7) << 1)) * 4] =
            pk4(e0, e1, e2, e3);
    }

    const int qiA = qbA + w * 16 + lm;
    const bool maskA = (k0 + 63 > qbA + w * 16);
    #pragma unroll
    for (int n = 0; n < 4; ++n) {
        const int kv0 = k0 + n * 16 + quad * 4;
        float e0, e1, e2, e3;
        if (maskA) {
            e0 = (kv0     > qiA) ? 0.f : __builtin_amdgcn_exp2f(stA[n][0]);
            e1 = (kv0 + 1 > qiA) ? 0.f : __builtin_amdgcn_exp2f(stA[n][1]);
            e2 = (kv0 + 2 > qiA) ? 0.f : __builtin_amdgcn_exp2f(stA[n][2]);
            e3 = (kv0 + 3 > qiA) ? 0.f : __builtin_amdgcn_exp2f(stA[n][3]);
        } else {
            e0 = __builtin_amdgcn_exp2f(stA[n][0]); e1 = __builtin_amdgcn_exp2f(stA[n][1]);
            e2 = __builtin_amdgcn_exp2f(stA[n][2]); e3 = __builtin_amdgcn_exp2f(stA[n][3]);
        }
        lA += (e0 + e1) + (e2 + e3);
        *(bf16x4*)&PtA[lm * PKS + ((n * 4 + quad) ^ ((lm & 7) << 1)) * 4] =
            pk4(e0, e1, e2, e3);
    }

    bf16x8 pB0 = *(const bf16x8*)&PtB[lm * PKS + kb0];
    bf16x8 pB1 = *(const bf16x8*)&PtB[lm * PKS + kb1];
    bf16x8 pA0 = *(const bf16x8*)&PtA[lm * PKS + kb0];
    bf16x8 pA1 = *(const bf16x8*)&PtA[lm * PKS + kb1];
    __builtin_amdgcn_s_setprio(1);
    #pragma unroll
    for (int dt = 0; dt < 4; ++dt) {
        bf16x8 vf0 = *(const bf16x8*)&Vs[(dt * 16 + lm) * RS + kb0];
        bf16x8 vf1 = *(const bf16x8*)&Vs[(dt * 16 + lm) * RS + kb1];
        oB[dt] = mfma16(vf0, pB0, oB[dt]);
        oB[dt] = mfma16(vf1, pB1, oB[dt]);
        oA[dt] = mfma16(vf0, pA0, oA[dt]);
        oA[dt] = mfma16(vf1, pA1, oA[dt]);
    }
    __builtin_amdgcn_s_setprio(0);
}

__device__ inline void attn_epilogue(
    f32x4 (&oacc)[4], float l,
    int qbase, int w, int lm, int quad, int b, int h, __bf16* o)
{
    float ls = l;
    ls += __shfl_xor(ls, 16);
    ls += __shfl_xor(ls, 32);
    float rinv = 1.0f / ls;
    const size_t rowbase = (size_t)(b * 2048 + qbase + w * 16 + lm) * 2048 + h * 64;
    #pragma unroll
    for (int dt = 0; dt < 4; ++dt) {
        *(bf16x4*)(o + rowbase + dt * 16 + quad * 4) =
            pk4(oacc[dt][0] * rinv, oacc[dt][1] * rinv,
                oacc[dt][2] * rinv, oacc[dt][3] * rinv);
    }
}

__global__ __launch_bounds__(512, 4) void attn_kernel(
    const __bf16* __restrict__ qkv, const __bf16* __restrict__ vt,
    __bf16* __restrict__ o)
{
    __shared__ __bf16 Ks[2][64 * RS];
    __shared__ __bf16 Vs[2][64 * RS];
    __shared__ __bf16 Pt[8][2][16 * PKS];
    const int tid  = threadIdx.x;
    const int w    = tid >> 6;
    const int lane = tid & 63;
    const int lm   = lane & 15;
    const int quad = lane >> 4;
    const int p = blockIdx.x, h = blockIdx.y, b = blockIdx.z;
    const int kvh = h >> 2;
    const int qbA = p * 128, qbB = (15 - p) * 128;
    const int ntA = 2 * p + 2, ntB = 32 - 2 * p;   // both even; ntA < ntB
    __bf16* PtwB = &Pt[w][0][0];
    __bf16* PtwA = &Pt[w][1][0];

    bf16x8 qfA[2], qfB[2];
    #pragma unroll
    for (int kh = 0; kh < 2; ++kh) {
        qfA[kh] = *(const bf16x8*)(qkv + (size_t)(b * 2048 + qbA + w * 16 + lm) * 3072
                                      + h * 64 + kh * 32 + quad * 8);
        qfB[kh] = *(const bf16x8*)(qkv + (size_t)(b * 2048 + qbB + w * 16 + lm) * 3072
                                      + h * 64 + kh * 32 + quad * 8);
    }

    f32x4 oA[4], oB[4];
    float lA = 0.f, lB = 0.f;
    #pragma unroll
    for (int j = 0; j < 4; ++j) {
        oA[j] = (f32x4){0.f, 0.f, 0.f, 0.f};
        oB[j] = (f32x4){0.f, 0.f, 0.f, 0.f};
    }

    const int srow = tid >> 3;
    const int scg  = (tid & 7) * 8;                          // global col
    const int scl  = (((tid & 7) ^ (srow & 7))) * 8;         // swizzled LDS col
    const __bf16* kbase = qkv + (size_t)(b * 2048) * 3072 + 2048 + kvh * 64;
    const __bf16* vbase = vt  + (size_t)(kvh * 64 + srow) * 4096 + b * 2048;

    // prefetch regs for tiles 0 and 1 (ntB >= 16 always)
    int4 kr0, vr0, kr1, vr1;
    kr0 = *(const int4*)(kbase + (size_t)srow * 3072 + scg);
    vr0 = *(const int4*)(vbase + scg);
    kr1 = *(const int4*)(kbase + (size_t)(64 + srow) * 3072 + scg);
    vr1 = *(const int4*)(vbase + 64 + scg);

    for (int kt = 0; kt < ntB; kt += 2) {
        const int k0 = kt * 64;
        *(int4*)&Ks[0][srow * RS + scl] = kr0;
        *(int4*)&Vs[0][srow * RS + scl] = vr0;
        *(int4*)&Ks[1][srow * RS + scl] = kr1;
        *(int4*)&Vs[1][srow * RS + scl] = vr1;
        if (kt + 2 < ntB) {
            kr0 = *(const int4*)(kbase + (size_t)(k0 + 128 + srow) * 3072 + scg);
            vr0 = *(const int4*)(vbase + k0 + 128 + scg);
            kr1 = *(const int4*)(kbase + (size_t)(k0 + 192 + srow) * 3072 + scg);
            vr1 = *(const int4*)(vbase + k0 + 192 + scg);
        }
        __syncthreads();
        if (kt < ntA) {   // ntA even -> whole pairs
            attn_tile2(qfA, qfB, oA, oB, lA, lB, qbA, k0, w, lm, quad,
                       Ks[0], Vs[0], PtwA, PtwB);
            attn_tile2(qfA, qfB, oA, oB, lA, lB, qbA, k0 + 64, w, lm, quad,
                       Ks[1], Vs[1], PtwA, PtwB);
        } else {
            attn_tile(qfB, oB, lB, qbB, k0, w, lm, quad, Ks[0], Vs[0], PtwB);
            attn_tile(qfB, oB, lB, qbB, k0 + 64, w, lm, quad, Ks[1], Vs[1], PtwB);
        }
        __syncthreads();
    }

    attn_epilogue(oA, lA, qbA, w, lm, quad, b, h, o);
    attn_epilogue(oB, lB, qbB, w, lm, quad, b, h, o);
}

// ---------------------------------------------------------------------------
extern "C" void kernel_launch(void* const* d_in, const int* in_sizes, int n_in,
                              void* d_out, int out_size, void* d_ws, size_t ws_size,
                              hipStream_t stream)
{
    const float* x  = (const float*)d_in[0];
    const float* Wq = (const float*)d_in[1];
    const float* Wk = (const float*)d_in[2];
    const float* Wv = (const float*)d_in[3];
    const float* Wo = (const float*)d_in[4];

    const size_t Mi = 1u << 20;
    // d_out (32 MiB fp32) is scratch until the final GEMM writes it.
    char* ob = (char*)d_out;
    __bf16* xb    = (__bf16*)ob;              // 16 MiB  [4096][2048]
    __bf16* wqkvb = (__bf16*)(ob + 16 * Mi);  // 12 MiB  [3072][2048]
    __bf16* vt    = (__bf16*)(ob + 28 * Mi);  //  4 MiB  [512][4096]
    // d_ws (>= 40 MiB, proven)
    char* ws = (char*)d_ws;
    __bf16* qkvc = (__bf16*)ws;               // 24 MiB  [4096][3072]  Q|K|V
    __bf16* aws  = (__bf16*)(ws + 24 * Mi);   // 16 MiB  [4096][2048]
    __bf16* wob  = (__bf16*)ws;               //  8 MiB, reuses qkvc after attn

    dim3 blk(256);
    cvt4_kernel<<<14336, blk, 0, stream>>>(x, Wq, Wk, Wv, xb, wqkvb);
    gemm_qkv<<<dim3(16, 16), dim3(512), 0, stream>>>(xb, wqkvb, qkvc, 4096, 3072, 2048);
    transpose_kernel<<<dim3(64, 8), blk, 0, stream>>>(qkvc + 2560, vt, 3072);
    attn_kernel<<<dim3(8, 32, 2), dim3(512), 0, stream>>>(qkvc, vt, aws);
    cvt_kernel<<<4096, blk, 0, stream>>>(Wo, wob, 1048576);
    gemm_o<<<dim3(16, 16), dim3(512), 0, stream>>>(aws, wob, (float*)d_out, 4096, 2048, 2048);
}

// Round 9
// 287.517 us; speedup vs baseline: 1.5278x; 1.5278x over previous
//
#include <hip/hip_runtime.h>

// ---------------------------------------------------------------------------
// GQA forward, fp32 I/O, bf16 MFMA compute.
// B=2 S=2048 D=2048 HQ=32 HKV=8 HD=64.
// ROUND-13 (recovery): known-good composite. cvt4 (head-col perm) ->
// QKV GEMM (256x192 relaxed 3-barrier, r7-measured) -> V transpose ->
// flash attn (r6 version: fused A/B paired-tile, dbuf, XOR swizzle, 59us) ->
// cvt(Wo) -> O GEMM (256x128 4-phase, r6-measured).
// ---------------------------------------------------------------------------

typedef __bf16 bf16x8 __attribute__((ext_vector_type(8)));
typedef __bf16 bf16x4 __attribute__((ext_vector_type(4)));
typedef float f32x4 __attribute__((ext_vector_type(4)));

__device__ inline f32x4 mfma16(bf16x8 a, bf16x8 b, f32x4 c) {
    return __builtin_amdgcn_mfma_f32_16x16x32_bf16(a, b, c, 0, 0, 0);
}

__device__ inline void gld16(const __bf16* g, __bf16* l) {
    __builtin_amdgcn_global_load_lds(
        (const __attribute__((address_space(1))) void*)g,
        (__attribute__((address_space(3))) void*)l, 16, 0, 0);
}

__device__ inline bf16x4 pk4(float a, float b, float c, float d) {
    bf16x4 r; r[0] = (__bf16)a; r[1] = (__bf16)b; r[2] = (__bf16)c; r[3] = (__bf16)d;
    return r;
}

// 1/sqrt(64) * log2(e): attn computes exp2(score) = exp(qk/8)
#define SCALE_Q 0.18033688011112042f
#define L2IF    0.4152410118609203f    // log2(10000)/32
#define INV2PI  0.15915494309189535f

// Head-column permutation: natural within-head d -> storage slot.
__device__ inline int permrow(int n) {
    int nod = n & 63;
    int hj = ((nod >> 5) & 1) | (((nod >> 4) & 1) << 1);
    return (n & ~63) | (hj << 4) | (nod & 15);
}

// ---------------- fused fp32->bf16 for x, Wq, Wk, Wv ------------------------
__global__ void cvt4_kernel(const float* __restrict__ x,  const float* __restrict__ wq,
                            const float* __restrict__ wk, const float* __restrict__ wv,
                            __bf16* __restrict__ xb, __bf16* __restrict__ wqkvb)
{
    int i = blockIdx.x * blockDim.x + threadIdx.x;
    const float* src; __bf16* dst;
    if (i < 2097152)      { src = x  + (size_t)i * 4;  dst = xb + (size_t)i * 4; }
    else if (i < 3145728) {
        int j = i - 2097152; int n = j >> 9; int off = (j & 511) * 4;
        src = wq + (size_t)j * 4;
        dst = wqkvb + (size_t)permrow(n) * 2048 + off;
    }
    else if (i < 3407872) {
        int j = i - 3145728; int n = j >> 9; int off = (j & 511) * 4;
        src = wk + (size_t)j * 4;
        dst = wqkvb + 4194304 + (size_t)permrow(n) * 2048 + off;
    }
    else                  { int j = i - 3407872; src = wv + (size_t)j * 4; dst = wqkvb + 5242880 + (size_t)j * 4; }
    float4 f = *(const float4*)src;
    *(bf16x4*)dst = pk4(f.x, f.y, f.z, f.w);
}

__global__ void cvt_kernel(const float* __restrict__ in, __bf16* __restrict__ out, int n4)
{
    int i = blockIdx.x * blockDim.x + threadIdx.x;
    if (i >= n4) return;
    float4 f = ((const float4*)in)[i];
    ((bf16x4*)out)[i] = pk4(f.x, f.y, f.z, f.w);
}

// ---------------- 256x192 GEMM (QKV): 3-barrier relaxed schedule ------------
__global__ __launch_bounds__(512, 2) void gemm_qkv(
    const __bf16* __restrict__ A, const __bf16* __restrict__ Bw,
    __bf16* __restrict__ C, int M, int N, int K)
{
    __shared__ __bf16 LA[2][16384];   // 256 x 64
    __shared__ __bf16 LB[2][12288];   // 192 x 64
    const int tid  = threadIdx.x;
    const int lane = tid & 63;
    const int w    = tid >> 6;
    const int lm   = lane & 15;
    const int quad = lane >> 4;
    const int wr   = w >> 1;     // 0..3 (M)
    const int wc   = w & 1;      // 0..1 (N)

    int bx, by;
    {
        int id  = blockIdx.x + gridDim.x * blockIdx.y;   // 256 wgs
        int swz = (id & 7) * 32 + (id >> 3);
        by = swz >> 4;
        bx = swz & 15;
    }
    const int m0 = by * 256;
    const int n0 = bx * 192;
    const int NT = K >> 6;

    const int srow = tid >> 3;
    const int scol = ((tid & 7) ^ (srow & 7)) * 8;   // pre-swizzled source col
    const int ldst = tid * 8;                        // linear LDS dest
    const __bf16* ga = A  + (size_t)(m0 + srow) * K + scol;
    const __bf16* gb = Bw + (size_t)(n0 + srow) * K + scol;

    auto STA = [&](int bf, int r, int u) {
        gld16(ga + (size_t)r * K + u * 64, &LA[bf][r * 64 + ldst]);
    };
    auto STB = [&](int bf, int r, int u) {
        gld16(gb + (size_t)r * K + u * 64, &LB[bf][r * 64 + ldst]);
    };

    f32x4 acc[4][6];
    #pragma unroll
    for (int i = 0; i < 4; ++i)
        #pragma unroll
        for (int j = 0; j < 6; ++j)
            acc[i][j] = (f32x4){0.f, 0.f, 0.f, 0.f};

    const int axo = (wr * 64 + lm) * 64;
    const int bxo = (wc * 96 + lm) * 64;
    const int ks0 = ((quad * 8)      ^ ((lm & 7) * 8));
    const int ks1 = ((32 + quad * 8) ^ ((lm & 7) * 8));

    STA(0, 0, 0); STA(0, 64, 0); STA(0, 128, 0); STA(0, 192, 0);
    STB(0, 0, 0); STB(0, 64, 0); STB(0, 128, 0);
    STA(1, 0, 1); STA(1, 64, 1); STA(1, 128, 1); STA(1, 192, 1);
    STB(1, 0, 1); STB(1, 64, 1); STB(1, 128, 1);
    asm volatile("s_waitcnt vmcnt(7)" ::: "memory");
    __builtin_amdgcn_s_barrier();
    asm volatile("" ::: "memory");

    bf16x8 A01[2][2], A23[2][2], B1[3][2], B2[3][2];
    for (int t = 0; t < NT; ++t) {
        const int b = t & 1;
        const __bf16* la = LA[b];
        const __bf16* lb = LB[b];
        #pragma unroll
        for (int mi = 0; mi < 2; ++mi) {
            A01[mi][0] = *(const bf16x8*)(la + axo + mi * 1024 + ks0);
            A01[mi][1] = *(const bf16x8*)(la + axo + mi * 1024 + ks1);
        }
        #pragma unroll
        for (int ni = 0; ni < 3; ++ni) {
            B1[ni][0] = *(const bf16x8*)(lb + bxo + ni * 1024 + ks0);
            B1[ni][1] = *(const bf16x8*)(lb + bxo + ni * 1024 + ks1);
        }
        #pragma unroll
        for (int ni = 0; ni < 3; ++ni) {
            B2[ni][0] = *(const bf16x8*)(lb + bxo + (ni + 3) * 1024 + ks0);
            B2[ni][1] = *(const bf16x8*)(lb + bxo + (ni + 3) * 1024 + ks1);
        }
        #pragma unroll
        for (int mi = 0; mi < 2; ++mi) {
            A23[mi][0] = *(const bf16x8*)(la + axo + (mi + 2) * 1024 + ks0);
            A23[mi][1] = *(const bf16x8*)(la + axo + (mi + 2) * 1024 + ks1);
        }
        __builtin_amdgcn_s_setprio(1);
        #pragma unroll
        for (int mi = 0; mi < 2; ++mi)
            #pragma unroll
            for (int ni = 0; ni < 3; ++ni) {
                acc[mi][ni] = mfma16(A01[mi][0], B1[ni][0], acc[mi][ni]);
                acc[mi][ni] = mfma16(A01[mi][1], B1[ni][1], acc[mi][ni]);
            }
        #pragma unroll
        for (int mi = 0; mi < 2; ++mi)
            #pragma unroll
            for (int ni = 0; ni < 3; ++ni) {
                acc[mi][ni + 3] = mfma16(A01[mi][0], B2[ni][0], acc[mi][ni + 3]);
                acc[mi][ni + 3] = mfma16(A01[mi][1], B2[ni][1], acc[mi][ni + 3]);
            }
        __builtin_amdgcn_s_setprio(0);
        asm volatile("s_waitcnt lgkmcnt(0)" ::: "memory");
        __builtin_amdgcn_s_barrier();
        asm volatile("" ::: "memory");
        if (t + 2 < NT) { STB(b, 0, t + 2); STB(b, 64, t + 2); STB(b, 128, t + 2); }
        __builtin_amdgcn_s_setprio(1);
        #pragma unroll
        for (int mi = 0; mi < 2; ++mi)
            #pragma unroll
            for (int ni = 0; ni < 3; ++ni) {
                acc[mi + 2][ni] = mfma16(A23[mi][0], B1[ni][0], acc[mi + 2][ni]);
                acc[mi + 2][ni] = mfma16(A23[mi][1], B1[ni][1], acc[mi + 2][ni]);
            }
        __builtin_amdgcn_s_setprio(0);
        __builtin_amdgcn_s_barrier();
        asm volatile("" ::: "memory");
        if (t + 2 < NT) {
            STA(b, 0, t + 2); STA(b, 64, t + 2);
            STA(b, 128, t + 2); STA(b, 192, t + 2);
        }
        __builtin_amdgcn_s_setprio(1);
        #pragma unroll
        for (int mi = 0; mi < 2; ++mi)
            #pragma unroll
            for (int ni = 0; ni < 3; ++ni) {
                acc[mi + 2][ni + 3] = mfma16(A23[mi][0], B2[ni][0], acc[mi + 2][ni + 3]);
                acc[mi + 2][ni + 3] = mfma16(A23[mi][1], B2[ni][1], acc[mi + 2][ni + 3]);
            }
        __builtin_amdgcn_s_setprio(0);
        if (t < NT - 2) asm volatile("s_waitcnt vmcnt(7)" ::: "memory");
        else            asm volatile("s_waitcnt vmcnt(0)" ::: "memory");
        __builtin_amdgcn_s_barrier();
        asm volatile("" ::: "memory");
    }

    // RoPE on permuted pairs: pair = (j even, j+1), freq idx = (hj>>1)*16+lm.
    {
        float invr[2];
        invr[0] = exp2f(-(float)lm        * L2IF) * INV2PI;
        invr[1] = exp2f(-(float)(16 + lm) * L2IF) * INV2PI;
        #pragma unroll
        for (int jp = 0; jp < 3; ++jp) {
            const int jlo = jp * 2;
            const int pcb = n0 + wc * 96 + jlo * 16;
            if (pcb >= 2560) continue;                 // V: no rope (wave-uniform)
            const int hj = (pcb >> 4) & 3;             // even
            const float fr = invr[hj >> 1];
            #pragma unroll
            for (int i = 0; i < 4; ++i)
                #pragma unroll
                for (int r = 0; r < 4; ++r) {
                    float tt = (float)((m0 + wr * 64 + i * 16 + quad * 4 + r) & 2047);
                    float aR = tt * fr;
                    aR -= floorf(aR);                  // revolutions
                    float cs = __builtin_amdgcn_cosf(aR);
                    float sn = __builtin_amdgcn_sinf(aR);
                    float x1 = acc[i][jlo][r], x2 = acc[i][jlo + 1][r];
                    acc[i][jlo][r]     = x1 * cs - x2 * sn;
                    acc[i][jlo + 1][r] = x2 * cs + x1 * sn;
                }
        }
    }

    // C-write: un-permute Q/K cols, scale Q.
    #pragma unroll
    for (int j = 0; j < 6; ++j) {
        const int pcb = n0 + wc * 96 + j * 16;
        int colb; float sc;
        if (pcb < 2560) {
            const int hj = (pcb >> 4) & 3;
            colb = (pcb & ~63) | ((hj & 1) << 5) | ((hj >> 1) << 4);
            sc = (pcb < 2048) ? SCALE_Q : 1.0f;
        } else { colb = pcb; sc = 1.0f; }
        #pragma unroll
        for (int i = 0; i < 4; ++i)
            #pragma unroll
            for (int r = 0; r < 4; ++r) {
                int row = m0 + wr * 64 + i * 16 + quad * 4 + r;
                C[(size_t)row * N + colb + lm] = (__bf16)(acc[i][j][r] * sc);
            }
    }
}

// ---------------- 256x128 4-phase GEMM (O proj): C fp32 (round-6 version) ---
__global__ __launch_bounds__(512, 2) void gemm_o(
    const __bf16* __restrict__ A, const __bf16* __restrict__ Bw,
    float* __restrict__ C, int M, int N, int K)
{
    __shared__ __bf16 LA[2][16384];   // 256x64
    __shared__ __bf16 LB[2][8192];    // 128x64
    const int tid  = threadIdx.x;
    const int lane = tid & 63;
    const int w    = tid >> 6;
    const int lm   = lane & 15;
    const int quad = lane >> 4;
    const int wr   = w >> 1;     // 0..3
    const int wc   = w & 1;      // 0..1

    int bx, by;
    {
        int id  = blockIdx.x + gridDim.x * blockIdx.y;   // 256 wgs
        int swz = (id & 7) * 32 + (id >> 3);
        by = swz >> 4;
        bx = swz & 15;
    }
    const int m0 = by * 256;
    const int n0 = bx * 128;
    const int NT = K >> 6;

    const int srow = tid >> 3;
    const int scol = ((tid & 7) ^ (srow & 7)) * 8;
    const int ldst = tid * 8;
    const __bf16* ga = A  + (size_t)(m0 + srow) * K + scol;
    const __bf16* gb = Bw + (size_t)(n0 + srow) * K + scol;

    auto STA = [&](int bf, int r, int u) {
        gld16(ga + (size_t)r * K + u * 64, &LA[bf][r * 64 + ldst]);
    };
    auto STB = [&](int bf, int r, int u) {
        gld16(gb + (size_t)r * K + u * 64, &LB[bf][r * 64 + ldst]);
    };

    f32x4 acc[4][4];
    #pragma unroll
    for (int i = 0; i < 4; ++i)
        #pragma unroll
        for (int j = 0; j < 4; ++j)
            acc[i][j] = (f32x4){0.f, 0.f, 0.f, 0.f};

    const int axo = (wr * 64 + lm) * 64;
    const int bxo = (wc * 64 + lm) * 64;
    const int ks0 = ((quad * 8)      ^ ((lm & 7) * 8));
    const int ks1 = ((32 + quad * 8) ^ ((lm & 7) * 8));

    STA(0, 0, 0); STA(0, 64, 0); STA(0, 128, 0); STA(0, 192, 0);
    STB(0, 0, 0); STB(0, 64, 0);
    STA(1, 0, 1); STA(1, 64, 1); STA(1, 128, 1); STA(1, 192, 1);
    STB(1, 0, 1); STB(1, 64, 1);
    asm volatile("s_waitcnt vmcnt(6)" ::: "memory");
    __builtin_amdgcn_s_barrier();
    asm volatile("" ::: "memory");

    bf16x8 Af[4][2], Bf[4][2];
    for (int t = 0; t < NT; ++t) {
        const int b = t & 1;
        const __bf16* la = LA[b];
        const __bf16* lb = LB[b];
        // ---- P1: read Af m0-1, Bf n0-1; MFMA (m01, n01)
        #pragma unroll
        for (int mi = 0; mi < 2; ++mi) {
            Af[mi][0] = *(const bf16x8*)(la + axo + mi * 1024 + ks0);
            Af[mi][1] = *(const bf16x8*)(la + axo + mi * 1024 + ks1);
        }
        #pragma unroll
        for (int ni = 0; ni < 2; ++ni) {
            Bf[ni][0] = *(const bf16x8*)(lb + bxo + ni * 1024 + ks0);
            Bf[ni][1] = *(const bf16x8*)(lb + bxo + ni * 1024 + ks1);
        }
        __builtin_amdgcn_s_barrier();
        asm volatile("s_waitcnt lgkmcnt(0)" ::: "memory");
        __builtin_amdgcn_s_setprio(1);
        #pragma unroll
        for (int mi = 0; mi < 2; ++mi)
            #pragma unroll
            for (int ni = 0; ni < 2; ++ni) {
                acc[mi][ni] = mfma16(Af[mi][0], Bf[ni][0], acc[mi][ni]);
                acc[mi][ni] = mfma16(Af[mi][1], Bf[ni][1], acc[mi][ni]);
            }
        __builtin_amdgcn_s_setprio(0);
        __builtin_amdgcn_s_barrier();
        // ---- P2: read Bf n2-3; MFMA (m01, n23)
        #pragma unroll
        for (int ni = 2; ni < 4; ++ni) {
            Bf[ni][0] = *(const bf16x8*)(lb + bxo + ni * 1024 + ks0);
            Bf[ni][1] = *(const bf16x8*)(lb + bxo + ni * 1024 + ks1);
        }
        __builtin_amdgcn_s_barrier();
        asm volatile("s_waitcnt lgkmcnt(0)" ::: "memory");
        __builtin_amdgcn_s_setprio(1);
        #pragma unroll
        for (int mi = 0; mi < 2; ++mi)
            #pragma unroll
            for (int ni = 2; ni < 4; ++ni) {
                acc[mi][ni] = mfma16(Af[mi][0], Bf[ni][0], acc[mi][ni]);
                acc[mi][ni] = mfma16(Af[mi][1], Bf[ni][1], acc[mi][ni]);
            }
        __builtin_amdgcn_s_setprio(0);
        __builtin_amdgcn_s_barrier();
        // ---- P3: read Af m2-3; stage B(t+2); MFMA (m23, n01)
        #pragma unroll
        for (int mi = 2; mi < 4; ++mi) {
            Af[mi][0] = *(const bf16x8*)(la + axo + mi * 1024 + ks0);
            Af[mi][1] = *(const bf16x8*)(la + axo + mi * 1024 + ks1);
        }
        if (t + 2 < NT) { STB(b, 0, t + 2); STB(b, 64, t + 2); }
        __builtin_amdgcn_s_barrier();
        asm volatile("s_waitcnt lgkmcnt(0)" ::: "memory");
        __builtin_amdgcn_s_setprio(1);
        #pragma unroll
        for (int mi = 2; mi < 4; ++mi)
            #pragma unroll
            for (int ni = 0; ni < 2; ++ni) {
                acc[mi][ni] = mfma16(Af[mi][0], Bf[ni][0], acc[mi][ni]);
                acc[mi][ni] = mfma16(Af[mi][1], Bf[ni][1], acc[mi][ni]);
            }
        __builtin_amdgcn_s_setprio(0);
        __builtin_amdgcn_s_barrier();
        // ---- P4: stage A(t+2); MFMA (m23, n23); counted vmcnt
        if (t + 2 < NT) {
            STA(b, 0, t + 2); STA(b, 64, t + 2);
            STA(b, 128, t + 2); STA(b, 192, t + 2);
        }
        __builtin_amdgcn_s_setprio(1);
        #pragma unroll
        for (int mi = 2; mi < 4; ++mi)
            #pragma unroll
            for (int ni = 2; ni < 4; ++ni) {
                acc[mi][ni] = mfma16(Af[mi][0], Bf[ni][0], acc[mi][ni]);
                acc[mi][ni] = mfma16(Af[mi][1], Bf[ni][1], acc[mi][ni]);
            }
        __builtin_amdgcn_s_setprio(0);
        if (t < NT - 2) asm volatile("s_waitcnt vmcnt(6)" ::: "memory");
        else            asm volatile("s_waitcnt vmcnt(0)" ::: "memory");
        __builtin_amdgcn_s_barrier();
        asm volatile("" ::: "memory");
    }

    #pragma unroll
    for (int i = 0; i < 4; ++i)
        #pragma unroll
        for (int j = 0; j < 4; ++j)
            #pragma unroll
            for (int r = 0; r < 4; ++r) {
                int row = m0 + wr * 64 + i * 16 + quad * 4 + r;
                int col = n0 + wc * 64 + j * 16 + lm;
                C[(size_t)row * N + col] = acc[i][j][r];
            }
}

// ---------------- V transpose: [4096 tok][512 d] (stride 3072) -> [512][4096]
__global__ __launch_bounds__(256) void transpose_kernel(
    const __bf16* __restrict__ in, __bf16* __restrict__ out, int rowstride)
{
    __shared__ __bf16 T[64][72];
    const int t0 = blockIdx.x * 64;
    const int d0 = blockIdx.y * 64;
    const int r = threadIdx.x >> 2, c = (threadIdx.x & 3) * 16;
    *(int4*)&T[r][c]     = *(const int4*)(in + (size_t)(t0 + r) * rowstride + d0 + c);
    *(int4*)&T[r][c + 8] = *(const int4*)(in + (size_t)(t0 + r) * rowstride + d0 + c + 8);
    __syncthreads();
    bf16x8 o0, o1;
    #pragma unroll
    for (int i = 0; i < 8; ++i) { o0[i] = T[c + i][r]; o1[i] = T[c + 8 + i][r]; }
    *(bf16x8*)(out + (size_t)(d0 + r) * 4096 + t0 + c)     = o0;
    *(bf16x8*)(out + (size_t)(d0 + r) * 4096 + t0 + c + 8) = o1;
}

// ---------------- Flash attention (round-6 version, 59us measured) ----------
#define RS  64
#define PKS 64

__device__ inline void attn_tile(
    const bf16x8 (&qf)[2], f32x4 (&oacc)[4], float& l,
    int qbase, int k0, int w, int lm, int quad,
    const __bf16* Ks, const __bf16* Vs, __bf16* Ptw)
{
    const int kb0 = (quad ^ (lm & 7)) * 8;
    const int kb1 = ((quad + 4) ^ (lm & 7)) * 8;
    f32x4 st[4];
    #pragma unroll
    for (int n = 0; n < 4; ++n)
        st[n] = (f32x4){0.f, 0.f, 0.f, 0.f};

    #pragma unroll
    for (int n = 0; n < 4; ++n) {
        bf16x8 kf0 = *(const bf16x8*)&Ks[(n * 16 + lm) * RS + kb0];
        bf16x8 kf1 = *(const bf16x8*)&Ks[(n * 16 + lm) * RS + kb1];
        st[n] = mfma16(kf0, qf[0], st[n]);
        st[n] = mfma16(kf1, qf[1], st[n]);
    }

    const int qi = qbase + w * 16 + lm;
    const bool any_mask = (k0 + 63 > qbase + w * 16);
    #pragma unroll
    for (int n = 0; n < 4; ++n) {
        const int kv0 = k0 + n * 16 + quad * 4;
        float e0, e1, e2, e3;
        if (any_mask) {
            e0 = (kv0     > qi) ? 0.f : __builtin_amdgcn_exp2f(st[n][0]);
            e1 = (kv0 + 1 > qi) ? 0.f : __builtin_amdgcn_exp2f(st[n][1]);
            e2 = (kv0 + 2 > qi) ? 0.f : __builtin_amdgcn_exp2f(st[n][2]);
            e3 = (kv0 + 3 > qi) ? 0.f : __builtin_amdgcn_exp2f(st[n][3]);
        } else {
            e0 = __builtin_amdgcn_exp2f(st[n][0]); e1 = __builtin_amdgcn_exp2f(st[n][1]);
            e2 = __builtin_amdgcn_exp2f(st[n][2]); e3 = __builtin_amdgcn_exp2f(st[n][3]);
        }
        l += (e0 + e1) + (e2 + e3);
        *(bf16x4*)&Ptw[lm * PKS + ((n * 4 + quad) ^ ((lm & 7) << 1)) * 4] =
            pk4(e0, e1, e2, e3);
    }

    bf16x8 pf0 = *(const bf16x8*)&Ptw[lm * PKS + kb0];
    bf16x8 pf1 = *(const bf16x8*)&Ptw[lm * PKS + kb1];
    #pragma unroll
    for (int dt = 0; dt < 4; ++dt) {
        bf16x8 vf0 = *(const bf16x8*)&Vs[(dt * 16 + lm) * RS + kb0];
        bf16x8 vf1 = *(const bf16x8*)&Vs[(dt * 16 + lm) * RS + kb1];
        oacc[dt] = mfma16(vf0, pf0, oacc[dt]);
        oacc[dt] = mfma16(vf1, pf1, oacc[dt]);
    }
}

__device__ inline void attn_tile2(
    const bf16x8 (&qfA)[2], const bf16x8 (&qfB)[2],
    f32x4 (&oA)[4], f32x4 (&oB)[4], float& lA, float& lB,
    int qbA, int k0, int w, int lm, int quad,
    const __bf16* Ks, const __bf16* Vs, __bf16* PtA, __bf16* PtB)
{
    const int kb0 = (quad ^ (lm & 7)) * 8;
    const int kb1 = ((quad + 4) ^ (lm & 7)) * 8;
    f32x4 stA[4], stB[4];
    #pragma unroll
    for (int n = 0; n < 4; ++n) {
        stA[n] = (f32x4){0.f, 0.f, 0.f, 0.f};
        stB[n] = (f32x4){0.f, 0.f, 0.f, 0.f};
    }

    #pragma unroll
    for (int n = 0; n < 4; ++n) {
        bf16x8 kf0 = *(const bf16x8*)&Ks[(n * 16 + lm) * RS + kb0];
        bf16x8 kf1 = *(const bf16x8*)&Ks[(n * 16 + lm) * RS + kb1];
        stB[n] = mfma16(kf0, qfB[0], stB[n]);
        stB[n] = mfma16(kf1, qfB[1], stB[n]);
        stA[n] = mfma16(kf0, qfA[0], stA[n]);
        stA[n] = mfma16(kf1, qfA[1], stA[n]);
    }

    #pragma unroll
    for (int n = 0; n < 4; ++n) {
        float e0 = __builtin_amdgcn_exp2f(stB[n][0]);
        float e1 = __builtin_amdgcn_exp2f(stB[n][1]);
        float e2 = __builtin_amdgcn_exp2f(stB[n][2]);
        float e3 = __builtin_amdgcn_exp2f(stB[n][3]);
        lB += (e0 + e1) + (e2 + e3);
        *(bf16x4*)&PtB[lm * PKS + ((n * 4 + quad) ^ ((lm & 7) << 1)) * 4] =
            pk4(e0, e1, e2, e3);
    }

    const int qiA = qbA + w * 16 + lm;
    const bool maskA = (k0 + 63 > qbA + w * 16);
    #pragma unroll
    for (int n = 0; n < 4; ++n) {
        const int kv0 = k0 + n * 16 + quad * 4;
        float e0, e1, e2, e3;
        if (maskA) {
            e0 = (kv0     > qiA) ? 0.f : __builtin_amdgcn_exp2f(stA[n][0]);
            e1 = (kv0 + 1 > qiA) ? 0.f : __builtin_amdgcn_exp2f(stA[n][1]);
            e2 = (kv0 + 2 > qiA) ? 0.f : __builtin_amdgcn_exp2f(stA[n][2]);
            e3 = (kv0 + 3 > qiA) ? 0.f : __builtin_amdgcn_exp2f(stA[n][3]);
        } else {
            e0 = __builtin_amdgcn_exp2f(stA[n][0]); e1 = __builtin_amdgcn_exp2f(stA[n][1]);
            e2 = __builtin_amdgcn_exp2f(stA[n][2]); e3 = __builtin_amdgcn_exp2f(stA[n][3]);
        }
        lA += (e0 + e1) + (e2 + e3);
        *(bf16x4*)&PtA[lm * PKS + ((n * 4 + quad) ^ ((lm & 7) << 1)) * 4] =
            pk4(e0, e1, e2, e3);
    }

    bf16x8 pB0 = *(const bf16x8*)&PtB[lm * PKS + kb0];
    bf16x8 pB1 = *(const bf16x8*)&PtB[lm * PKS + kb1];
    bf16x8 pA0 = *(const bf16x8*)&PtA[lm * PKS + kb0];
    bf16x8 pA1 = *(const bf16x8*)&PtA[lm * PKS + kb1];
    #pragma unroll
    for (int dt = 0; dt < 4; ++dt) {
        bf16x8 vf0 = *(const bf16x8*)&Vs[(dt * 16 + lm) * RS + kb0];
        bf16x8 vf1 = *(const bf16x8*)&Vs[(dt * 16 + lm) * RS + kb1];
        oB[dt] = mfma16(vf0, pB0, oB[dt]);
        oB[dt] = mfma16(vf1, pB1, oB[dt]);
        oA[dt] = mfma16(vf0, pA0, oA[dt]);
        oA[dt] = mfma16(vf1, pA1, oA[dt]);
    }
}

__device__ inline void attn_epilogue(
    f32x4 (&oacc)[4], float l,
    int qbase, int w, int lm, int quad, int b, int h, __bf16* o)
{
    float ls = l;
    ls += __shfl_xor(ls, 16);
    ls += __shfl_xor(ls, 32);
    float rinv = 1.0f / ls;
    const size_t rowbase = (size_t)(b * 2048 + qbase + w * 16 + lm) * 2048 + h * 64;
    #pragma unroll
    for (int dt = 0; dt < 4; ++dt) {
        *(bf16x4*)(o + rowbase + dt * 16 + quad * 4) =
            pk4(oacc[dt][0] * rinv, oacc[dt][1] * rinv,
                oacc[dt][2] * rinv, oacc[dt][3] * rinv);
    }
}

__global__ __launch_bounds__(512, 4) void attn_kernel(
    const __bf16* __restrict__ qkv, const __bf16* __restrict__ vt,
    __bf16* __restrict__ o)
{
    __shared__ __bf16 Ks[2][64 * RS];
    __shared__ __bf16 Vs[2][64 * RS];
    __shared__ __bf16 Pt[8][2][16 * PKS];
    const int tid  = threadIdx.x;
    const int w    = tid >> 6;
    const int lane = tid & 63;
    const int lm   = lane & 15;
    const int quad = lane >> 4;
    const int p = blockIdx.x, h = blockIdx.y, b = blockIdx.z;
    const int kvh = h >> 2;
    const int qbA = p * 128, qbB = (15 - p) * 128;
    const int ntA = 2 * p + 2, ntB = 32 - 2 * p;
    __bf16* PtwB = &Pt[w][0][0];
    __bf16* PtwA = &Pt[w][1][0];

    bf16x8 qfA[2], qfB[2];
    #pragma unroll
    for (int kh = 0; kh < 2; ++kh) {
        qfA[kh] = *(const bf16x8*)(qkv + (size_t)(b * 2048 + qbA + w * 16 + lm) * 3072
                                      + h * 64 + kh * 32 + quad * 8);
        qfB[kh] = *(const bf16x8*)(qkv + (size_t)(b * 2048 + qbB + w * 16 + lm) * 3072
                                      + h * 64 + kh * 32 + quad * 8);
    }

    f32x4 oA[4], oB[4];
    float lA = 0.f, lB = 0.f;
    #pragma unroll
    for (int j = 0; j < 4; ++j) {
        oA[j] = (f32x4){0.f, 0.f, 0.f, 0.f};
        oB[j] = (f32x4){0.f, 0.f, 0.f, 0.f};
    }

    const int srow = tid >> 3;
    const int scg  = (tid & 7) * 8;                          // global col
    const int scl  = (((tid & 7) ^ (srow & 7))) * 8;         // swizzled LDS col
    const __bf16* kbase = qkv + (size_t)(b * 2048) * 3072 + 2048 + kvh * 64;
    const __bf16* vbase = vt  + (size_t)(kvh * 64 + srow) * 4096 + b * 2048;

    int4 kr0, vr0;
    kr0 = *(const int4*)(kbase + (size_t)srow * 3072 + scg);
    vr0 = *(const int4*)(vbase + scg);

    for (int kt = 0; kt < ntB; ++kt) {
        const int c = kt & 1;
        const int k0 = kt * 64;
        *(int4*)&Ks[c][srow * RS + scl] = kr0;
        *(int4*)&Vs[c][srow * RS + scl] = vr0;
        if (kt + 1 < ntB) {
            kr0 = *(const int4*)(kbase + (size_t)(k0 + 64 + srow) * 3072 + scg);
            vr0 = *(const int4*)(vbase + k0 + 64 + scg);
        }
        __syncthreads();
        if (kt < ntA)
            attn_tile2(qfA, qfB, oA, oB, lA, lB, qbA, k0, w, lm, quad,
                       Ks[c], Vs[c], PtwA, PtwB);
        else
            attn_tile(qfB, oB, lB, qbB, k0, w, lm, quad, Ks[c], Vs[c], PtwB);
    }

    attn_epilogue(oA, lA, qbA, w, lm, quad, b, h, o);
    attn_epilogue(oB, lB, qbB, w, lm, quad, b, h, o);
}

// ---------------------------------------------------------------------------
extern "C" void kernel_launch(void* const* d_in, const int* in_sizes, int n_in,
                              void* d_out, int out_size, void* d_ws, size_t ws_size,
                              hipStream_t stream)
{
    const float* x  = (const float*)d_in[0];
    const float* Wq = (const float*)d_in[1];
    const float* Wk = (const float*)d_in[2];
    const float* Wv = (const float*)d_in[3];
    const float* Wo = (const float*)d_in[4];

    const size_t Mi = 1u << 20;
    // d_out (32 MiB fp32) is scratch until the final GEMM writes it.
    char* ob = (char*)d_out;
    __bf16* xb    = (__bf16*)ob;              // 16 MiB  [4096][2048]
    __bf16* wqkvb = (__bf16*)(ob + 16 * Mi);  // 12 MiB  [3072][2048]
    __bf16* vt    = (__bf16*)(ob + 28 * Mi);  //  4 MiB  [512][4096]
    // d_ws (>= 40 MiB, proven)
    char* ws = (char*)d_ws;
    __bf16* qkvc = (__bf16*)ws;               // 24 MiB  [4096][3072]  Q|K|V
    __bf16* aws  = (__bf16*)(ws + 24 * Mi);   // 16 MiB  [4096][2048]
    __bf16* wob  = (__bf16*)ws;               //  8 MiB, reuses qkvc after attn

    dim3 blk(256);
    cvt4_kernel<<<14336, blk, 0, stream>>>(x, Wq, Wk, Wv, xb, wqkvb);
    gemm_qkv<<<dim3(16, 16), dim3(512), 0, stream>>>(xb, wqkvb, qkvc, 4096, 3072, 2048);
    transpose_kernel<<<dim3(64, 8), blk, 0, stream>>>(qkvc + 2560, vt, 3072);
    attn_kernel<<<dim3(8, 32, 2), dim3(512), 0, stream>>>(qkvc, vt, aws);
    cvt_kernel<<<4096, blk, 0, stream>>>(Wo, wob, 1048576);
    gemm_o<<<dim3(16, 16), dim3(512), 0, stream>>>(aws, wob, (float*)d_out, 4096, 2048, 2048);
}

// Round 10
// 275.627 us; speedup vs baseline: 1.5937x; 1.0431x over previous
//
#include <hip/hip_runtime.h>

// ---------------------------------------------------------------------------
// GQA forward, fp32 I/O, bf16 MFMA compute.
// B=2 S=2048 D=2048 HQ=32 HKV=8 HD=64.
// ROUND-14: kernel-count reduction. cvt4 (head-col perm, + Wo fold when ws
// allows) -> QKV GEMM (256x192 relaxed 3-barrier; V written DIRECTLY to vt
// transposed -- transpose kernel eliminated) -> flash attn (r6 version) ->
// [cvt(Wo) only if ws==40Mi] -> O GEMM (256x128 4-phase r6).
// ---------------------------------------------------------------------------

typedef __bf16 bf16x8 __attribute__((ext_vector_type(8)));
typedef __bf16 bf16x4 __attribute__((ext_vector_type(4)));
typedef float f32x4 __attribute__((ext_vector_type(4)));

__device__ inline f32x4 mfma16(bf16x8 a, bf16x8 b, f32x4 c) {
    return __builtin_amdgcn_mfma_f32_16x16x32_bf16(a, b, c, 0, 0, 0);
}

__device__ inline void gld16(const __bf16* g, __bf16* l) {
    __builtin_amdgcn_global_load_lds(
        (const __attribute__((address_space(1))) void*)g,
        (__attribute__((address_space(3))) void*)l, 16, 0, 0);
}

__device__ inline bf16x4 pk4(float a, float b, float c, float d) {
    bf16x4 r; r[0] = (__bf16)a; r[1] = (__bf16)b; r[2] = (__bf16)c; r[3] = (__bf16)d;
    return r;
}

// 1/sqrt(64) * log2(e): attn computes exp2(score) = exp(qk/8)
#define SCALE_Q 0.18033688011112042f
#define L2IF    0.4152410118609203f    // log2(10000)/32
#define INV2PI  0.15915494309189535f

// Head-column permutation: natural within-head d -> storage slot.
__device__ inline int permrow(int n) {
    int nod = n & 63;
    int hj = ((nod >> 5) & 1) | (((nod >> 4) & 1) << 1);
    return (n & ~63) | (hj << 4) | (nod & 15);
}

// ---------------- fused fp32->bf16 for x, Wq, Wk, Wv (+ optional Wo) --------
__global__ void cvt4_kernel(const float* __restrict__ x,  const float* __restrict__ wq,
                            const float* __restrict__ wk, const float* __restrict__ wv,
                            const float* __restrict__ wo,
                            __bf16* __restrict__ xb, __bf16* __restrict__ wqkvb,
                            __bf16* __restrict__ wob)
{
    int i = blockIdx.x * blockDim.x + threadIdx.x;
    const float* src; __bf16* dst;
    if (i < 2097152)      { src = x  + (size_t)i * 4;  dst = xb + (size_t)i * 4; }
    else if (i < 3145728) {
        int j = i - 2097152; int n = j >> 9; int off = (j & 511) * 4;
        src = wq + (size_t)j * 4;
        dst = wqkvb + (size_t)permrow(n) * 2048 + off;
    }
    else if (i < 3407872) {
        int j = i - 3145728; int n = j >> 9; int off = (j & 511) * 4;
        src = wk + (size_t)j * 4;
        dst = wqkvb + 4194304 + (size_t)permrow(n) * 2048 + off;
    }
    else if (i < 3670016) { int j = i - 3407872; src = wv + (size_t)j * 4; dst = wqkvb + 5242880 + (size_t)j * 4; }
    else                  { int j = i - 3670016; src = wo + (size_t)j * 4; dst = wob + (size_t)j * 4; }
    float4 f = *(const float4*)src;
    *(bf16x4*)dst = pk4(f.x, f.y, f.z, f.w);
}

__global__ void cvt_kernel(const float* __restrict__ in, __bf16* __restrict__ out, int n4)
{
    int i = blockIdx.x * blockDim.x + threadIdx.x;
    if (i >= n4) return;
    float4 f = ((const float4*)in)[i];
    ((bf16x4*)out)[i] = pk4(f.x, f.y, f.z, f.w);
}

// ---------------- 256x192 GEMM (QKV): 3-barrier relaxed schedule ------------
// V columns (>= 2560) are written directly to VT transposed; Q/K to C.
__global__ __launch_bounds__(512, 2) void gemm_qkv(
    const __bf16* __restrict__ A, const __bf16* __restrict__ Bw,
    __bf16* __restrict__ C, __bf16* __restrict__ VT, int M, int N, int K)
{
    __shared__ __bf16 LA[2][16384];   // 256 x 64
    __shared__ __bf16 LB[2][12288];   // 192 x 64
    const int tid  = threadIdx.x;
    const int lane = tid & 63;
    const int w    = tid >> 6;
    const int lm   = lane & 15;
    const int quad = lane >> 4;
    const int wr   = w >> 1;     // 0..3 (M)
    const int wc   = w & 1;      // 0..1 (N)

    int bx, by;
    {
        int id  = blockIdx.x + gridDim.x * blockIdx.y;   // 256 wgs
        int swz = (id & 7) * 32 + (id >> 3);
        by = swz >> 4;
        bx = swz & 15;
    }
    const int m0 = by * 256;
    const int n0 = bx * 192;
    const int NT = K >> 6;

    const int srow = tid >> 3;
    const int scol = ((tid & 7) ^ (srow & 7)) * 8;   // pre-swizzled source col
    const int ldst = tid * 8;                        // linear LDS dest
    const __bf16* ga = A  + (size_t)(m0 + srow) * K + scol;
    const __bf16* gb = Bw + (size_t)(n0 + srow) * K + scol;

    auto STA = [&](int bf, int r, int u) {
        gld16(ga + (size_t)r * K + u * 64, &LA[bf][r * 64 + ldst]);
    };
    auto STB = [&](int bf, int r, int u) {
        gld16(gb + (size_t)r * K + u * 64, &LB[bf][r * 64 + ldst]);
    };

    f32x4 acc[4][6];
    #pragma unroll
    for (int i = 0; i < 4; ++i)
        #pragma unroll
        for (int j = 0; j < 6; ++j)
            acc[i][j] = (f32x4){0.f, 0.f, 0.f, 0.f};

    const int axo = (wr * 64 + lm) * 64;
    const int bxo = (wc * 96 + lm) * 64;
    const int ks0 = ((quad * 8)      ^ ((lm & 7) * 8));
    const int ks1 = ((32 + quad * 8) ^ ((lm & 7) * 8));

    STA(0, 0, 0); STA(0, 64, 0); STA(0, 128, 0); STA(0, 192, 0);
    STB(0, 0, 0); STB(0, 64, 0); STB(0, 128, 0);
    STA(1, 0, 1); STA(1, 64, 1); STA(1, 128, 1); STA(1, 192, 1);
    STB(1, 0, 1); STB(1, 64, 1); STB(1, 128, 1);
    asm volatile("s_waitcnt vmcnt(7)" ::: "memory");
    __builtin_amdgcn_s_barrier();
    asm volatile("" ::: "memory");

    bf16x8 A01[2][2], A23[2][2], B1[3][2], B2[3][2];
    for (int t = 0; t < NT; ++t) {
        const int b = t & 1;
        const __bf16* la = LA[b];
        const __bf16* lb = LB[b];
        #pragma unroll
        for (int mi = 0; mi < 2; ++mi) {
            A01[mi][0] = *(const bf16x8*)(la + axo + mi * 1024 + ks0);
            A01[mi][1] = *(const bf16x8*)(la + axo + mi * 1024 + ks1);
        }
        #pragma unroll
        for (int ni = 0; ni < 3; ++ni) {
            B1[ni][0] = *(const bf16x8*)(lb + bxo + ni * 1024 + ks0);
            B1[ni][1] = *(const bf16x8*)(lb + bxo + ni * 1024 + ks1);
        }
        #pragma unroll
        for (int ni = 0; ni < 3; ++ni) {
            B2[ni][0] = *(const bf16x8*)(lb + bxo + (ni + 3) * 1024 + ks0);
            B2[ni][1] = *(const bf16x8*)(lb + bxo + (ni + 3) * 1024 + ks1);
        }
        #pragma unroll
        for (int mi = 0; mi < 2; ++mi) {
            A23[mi][0] = *(const bf16x8*)(la + axo + (mi + 2) * 1024 + ks0);
            A23[mi][1] = *(const bf16x8*)(la + axo + (mi + 2) * 1024 + ks1);
        }
        __builtin_amdgcn_s_setprio(1);
        #pragma unroll
        for (int mi = 0; mi < 2; ++mi)
            #pragma unroll
            for (int ni = 0; ni < 3; ++ni) {
                acc[mi][ni] = mfma16(A01[mi][0], B1[ni][0], acc[mi][ni]);
                acc[mi][ni] = mfma16(A01[mi][1], B1[ni][1], acc[mi][ni]);
            }
        #pragma unroll
        for (int mi = 0; mi < 2; ++mi)
            #pragma unroll
            for (int ni = 0; ni < 3; ++ni) {
                acc[mi][ni + 3] = mfma16(A01[mi][0], B2[ni][0], acc[mi][ni + 3]);
                acc[mi][ni + 3] = mfma16(A01[mi][1], B2[ni][1], acc[mi][ni + 3]);
            }
        __builtin_amdgcn_s_setprio(0);
        asm volatile("s_waitcnt lgkmcnt(0)" ::: "memory");
        __builtin_amdgcn_s_barrier();
        asm volatile("" ::: "memory");
        if (t + 2 < NT) { STB(b, 0, t + 2); STB(b, 64, t + 2); STB(b, 128, t + 2); }
        __builtin_amdgcn_s_setprio(1);
        #pragma unroll
        for (int mi = 0; mi < 2; ++mi)
            #pragma unroll
            for (int ni = 0; ni < 3; ++ni) {
                acc[mi + 2][ni] = mfma16(A23[mi][0], B1[ni][0], acc[mi + 2][ni]);
                acc[mi + 2][ni] = mfma16(A23[mi][1], B1[ni][1], acc[mi + 2][ni]);
            }
        __builtin_amdgcn_s_setprio(0);
        __builtin_amdgcn_s_barrier();
        asm volatile("" ::: "memory");
        if (t + 2 < NT) {
            STA(b, 0, t + 2); STA(b, 64, t + 2);
            STA(b, 128, t + 2); STA(b, 192, t + 2);
        }
        __builtin_amdgcn_s_setprio(1);
        #pragma unroll
        for (int mi = 0; mi < 2; ++mi)
            #pragma unroll
            for (int ni = 0; ni < 3; ++ni) {
                acc[mi + 2][ni + 3] = mfma16(A23[mi][0], B2[ni][0], acc[mi + 2][ni + 3]);
                acc[mi + 2][ni + 3] = mfma16(A23[mi][1], B2[ni][1], acc[mi + 2][ni + 3]);
            }
        __builtin_amdgcn_s_setprio(0);
        if (t < NT - 2) asm volatile("s_waitcnt vmcnt(7)" ::: "memory");
        else            asm volatile("s_waitcnt vmcnt(0)" ::: "memory");
        __builtin_amdgcn_s_barrier();
        asm volatile("" ::: "memory");
    }

    // RoPE on permuted pairs: pair = (j even, j+1), freq idx = (hj>>1)*16+lm.
    {
        float invr[2];
        invr[0] = exp2f(-(float)lm        * L2IF) * INV2PI;
        invr[1] = exp2f(-(float)(16 + lm) * L2IF) * INV2PI;
        #pragma unroll
        for (int jp = 0; jp < 3; ++jp) {
            const int jlo = jp * 2;
            const int pcb = n0 + wc * 96 + jlo * 16;
            if (pcb >= 2560) continue;                 // V: no rope (wave-uniform)
            const int hj = (pcb >> 4) & 3;             // even
            const float fr = invr[hj >> 1];
            #pragma unroll
            for (int i = 0; i < 4; ++i)
                #pragma unroll
                for (int r = 0; r < 4; ++r) {
                    float tt = (float)((m0 + wr * 64 + i * 16 + quad * 4 + r) & 2047);
                    float aR = tt * fr;
                    aR -= floorf(aR);                  // revolutions
                    float cs = __builtin_amdgcn_cosf(aR);
                    float sn = __builtin_amdgcn_sinf(aR);
                    float x1 = acc[i][jlo][r], x2 = acc[i][jlo + 1][r];
                    acc[i][jlo][r]     = x1 * cs - x2 * sn;
                    acc[i][jlo + 1][r] = x2 * cs + x1 * sn;
                }
        }
    }

    // C-write: Q/K un-permute + scale to C; V directly transposed to VT.
    #pragma unroll
    for (int j = 0; j < 6; ++j) {
        const int pcb = n0 + wc * 96 + j * 16;
        if (pcb >= 2560) {
            const int dg = pcb + lm - 2560;            // V feature index 0..511
            #pragma unroll
            for (int i = 0; i < 4; ++i) {
                int row0 = m0 + wr * 64 + i * 16 + quad * 4;
                *(bf16x4*)(VT + (size_t)dg * 4096 + row0) =
                    pk4(acc[i][j][0], acc[i][j][1], acc[i][j][2], acc[i][j][3]);
            }
        } else {
            const int hj = (pcb >> 4) & 3;
            const int colb = (pcb & ~63) | ((hj & 1) << 5) | ((hj >> 1) << 4);
            const float sc = (pcb < 2048) ? SCALE_Q : 1.0f;
            #pragma unroll
            for (int i = 0; i < 4; ++i)
                #pragma unroll
                for (int r = 0; r < 4; ++r) {
                    int row = m0 + wr * 64 + i * 16 + quad * 4 + r;
                    C[(size_t)row * N + colb + lm] = (__bf16)(acc[i][j][r] * sc);
                }
        }
    }
}

// ---------------- 256x128 4-phase GEMM (O proj): C fp32 (round-6 version) ---
__global__ __launch_bounds__(512, 2) void gemm_o(
    const __bf16* __restrict__ A, const __bf16* __restrict__ Bw,
    float* __restrict__ C, int M, int N, int K)
{
    __shared__ __bf16 LA[2][16384];   // 256x64
    __shared__ __bf16 LB[2][8192];    // 128x64
    const int tid  = threadIdx.x;
    const int lane = tid & 63;
    const int w    = tid >> 6;
    const int lm   = lane & 15;
    const int quad = lane >> 4;
    const int wr   = w >> 1;     // 0..3
    const int wc   = w & 1;      // 0..1

    int bx, by;
    {
        int id  = blockIdx.x + gridDim.x * blockIdx.y;   // 256 wgs
        int swz = (id & 7) * 32 + (id >> 3);
        by = swz >> 4;
        bx = swz & 15;
    }
    const int m0 = by * 256;
    const int n0 = bx * 128;
    const int NT = K >> 6;

    const int srow = tid >> 3;
    const int scol = ((tid & 7) ^ (srow & 7)) * 8;
    const int ldst = tid * 8;
    const __bf16* ga = A  + (size_t)(m0 + srow) * K + scol;
    const __bf16* gb = Bw + (size_t)(n0 + srow) * K + scol;

    auto STA = [&](int bf, int r, int u) {
        gld16(ga + (size_t)r * K + u * 64, &LA[bf][r * 64 + ldst]);
    };
    auto STB = [&](int bf, int r, int u) {
        gld16(gb + (size_t)r * K + u * 64, &LB[bf][r * 64 + ldst]);
    };

    f32x4 acc[4][4];
    #pragma unroll
    for (int i = 0; i < 4; ++i)
        #pragma unroll
        for (int j = 0; j < 4; ++j)
            acc[i][j] = (f32x4){0.f, 0.f, 0.f, 0.f};

    const int axo = (wr * 64 + lm) * 64;
    const int bxo = (wc * 64 + lm) * 64;
    const int ks0 = ((quad * 8)      ^ ((lm & 7) * 8));
    const int ks1 = ((32 + quad * 8) ^ ((lm & 7) * 8));

    STA(0, 0, 0); STA(0, 64, 0); STA(0, 128, 0); STA(0, 192, 0);
    STB(0, 0, 0); STB(0, 64, 0);
    STA(1, 0, 1); STA(1, 64, 1); STA(1, 128, 1); STA(1, 192, 1);
    STB(1, 0, 1); STB(1, 64, 1);
    asm volatile("s_waitcnt vmcnt(6)" ::: "memory");
    __builtin_amdgcn_s_barrier();
    asm volatile("" ::: "memory");

    bf16x8 Af[4][2], Bf[4][2];
    for (int t = 0; t < NT; ++t) {
        const int b = t & 1;
        const __bf16* la = LA[b];
        const __bf16* lb = LB[b];
        // ---- P1: read Af m0-1, Bf n0-1; MFMA (m01, n01)
        #pragma unroll
        for (int mi = 0; mi < 2; ++mi) {
            Af[mi][0] = *(const bf16x8*)(la + axo + mi * 1024 + ks0);
            Af[mi][1] = *(const bf16x8*)(la + axo + mi * 1024 + ks1);
        }
        #pragma unroll
        for (int ni = 0; ni < 2; ++ni) {
            Bf[ni][0] = *(const bf16x8*)(lb + bxo + ni * 1024 + ks0);
            Bf[ni][1] = *(const bf16x8*)(lb + bxo + ni * 1024 + ks1);
        }
        __builtin_amdgcn_s_barrier();
        asm volatile("s_waitcnt lgkmcnt(0)" ::: "memory");
        __builtin_amdgcn_s_setprio(1);
        #pragma unroll
        for (int mi = 0; mi < 2; ++mi)
            #pragma unroll
            for (int ni = 0; ni < 2; ++ni) {
                acc[mi][ni] = mfma16(Af[mi][0], Bf[ni][0], acc[mi][ni]);
                acc[mi][ni] = mfma16(Af[mi][1], Bf[ni][1], acc[mi][ni]);
            }
        __builtin_amdgcn_s_setprio(0);
        __builtin_amdgcn_s_barrier();
        // ---- P2: read Bf n2-3; MFMA (m01, n23)
        #pragma unroll
        for (int ni = 2; ni < 4; ++ni) {
            Bf[ni][0] = *(const bf16x8*)(lb + bxo + ni * 1024 + ks0);
            Bf[ni][1] = *(const bf16x8*)(lb + bxo + ni * 1024 + ks1);
        }
        __builtin_amdgcn_s_barrier();
        asm volatile("s_waitcnt lgkmcnt(0)" ::: "memory");
        __builtin_amdgcn_s_setprio(1);
        #pragma unroll
        for (int mi = 0; mi < 2; ++mi)
            #pragma unroll
            for (int ni = 2; ni < 4; ++ni) {
                acc[mi][ni] = mfma16(Af[mi][0], Bf[ni][0], acc[mi][ni]);
                acc[mi][ni] = mfma16(Af[mi][1], Bf[ni][1], acc[mi][ni]);
            }
        __builtin_amdgcn_s_setprio(0);
        __builtin_amdgcn_s_barrier();
        // ---- P3: read Af m2-3; stage B(t+2); MFMA (m23, n01)
        #pragma unroll
        for (int mi = 2; mi < 4; ++mi) {
            Af[mi][0] = *(const bf16x8*)(la + axo + mi * 1024 + ks0);
            Af[mi][1] = *(const bf16x8*)(la + axo + mi * 1024 + ks1);
        }
        if (t + 2 < NT) { STB(b, 0, t + 2); STB(b, 64, t + 2); }
        __builtin_amdgcn_s_barrier();
        asm volatile("s_waitcnt lgkmcnt(0)" ::: "memory");
        __builtin_amdgcn_s_setprio(1);
        #pragma unroll
        for (int mi = 2; mi < 4; ++mi)
            #pragma unroll
            for (int ni = 0; ni < 2; ++ni) {
                acc[mi][ni] = mfma16(Af[mi][0], Bf[ni][0], acc[mi][ni]);
                acc[mi][ni] = mfma16(Af[mi][1], Bf[ni][1], acc[mi][ni]);
            }
        __builtin_amdgcn_s_setprio(0);
        __builtin_amdgcn_s_barrier();
        // ---- P4: stage A(t+2); MFMA (m23, n23); counted vmcnt
        if (t + 2 < NT) {
            STA(b, 0, t + 2); STA(b, 64, t + 2);
            STA(b, 128, t + 2); STA(b, 192, t + 2);
        }
        __builtin_amdgcn_s_setprio(1);
        #pragma unroll
        for (int mi = 2; mi < 4; ++mi)
            #pragma unroll
            for (int ni = 2; ni < 4; ++ni) {
                acc[mi][ni] = mfma16(Af[mi][0], Bf[ni][0], acc[mi][ni]);
                acc[mi][ni] = mfma16(Af[mi][1], Bf[ni][1], acc[mi][ni]);
            }
        __builtin_amdgcn_s_setprio(0);
        if (t < NT - 2) asm volatile("s_waitcnt vmcnt(6)" ::: "memory");
        else            asm volatile("s_waitcnt vmcnt(0)" ::: "memory");
        __builtin_amdgcn_s_barrier();
        asm volatile("" ::: "memory");
    }

    #pragma unroll
    for (int i = 0; i < 4; ++i)
        #pragma unroll
        for (int j = 0; j < 4; ++j)
            #pragma unroll
            for (int r = 0; r < 4; ++r) {
                int row = m0 + wr * 64 + i * 16 + quad * 4 + r;
                int col = n0 + wc * 64 + j * 16 + lm;
                C[(size_t)row * N + col] = acc[i][j][r];
            }
}

// ---------------- Flash attention (round-6 version, 59us measured) ----------
#define RS  64
#define PKS 64

__device__ inline void attn_tile(
    const bf16x8 (&qf)[2], f32x4 (&oacc)[4], float& l,
    int qbase, int k0, int w, int lm, int quad,
    const __bf16* Ks, const __bf16* Vs, __bf16* Ptw)
{
    const int kb0 = (quad ^ (lm & 7)) * 8;
    const int kb1 = ((quad + 4) ^ (lm & 7)) * 8;
    f32x4 st[4];
    #pragma unroll
    for (int n = 0; n < 4; ++n)
        st[n] = (f32x4){0.f, 0.f, 0.f, 0.f};

    #pragma unroll
    for (int n = 0; n < 4; ++n) {
        bf16x8 kf0 = *(const bf16x8*)&Ks[(n * 16 + lm) * RS + kb0];
        bf16x8 kf1 = *(const bf16x8*)&Ks[(n * 16 + lm) * RS + kb1];
        st[n] = mfma16(kf0, qf[0], st[n]);
        st[n] = mfma16(kf1, qf[1], st[n]);
    }

    const int qi = qbase + w * 16 + lm;
    const bool any_mask = (k0 + 63 > qbase + w * 16);
    #pragma unroll
    for (int n = 0; n < 4; ++n) {
        const int kv0 = k0 + n * 16 + quad * 4;
        float e0, e1, e2, e3;
        if (any_mask) {
            e0 = (kv0     > qi) ? 0.f : __builtin_amdgcn_exp2f(st[n][0]);
            e1 = (kv0 + 1 > qi) ? 0.f : __builtin_amdgcn_exp2f(st[n][1]);
            e2 = (kv0 + 2 > qi) ? 0.f : __builtin_amdgcn_exp2f(st[n][2]);
            e3 = (kv0 + 3 > qi) ? 0.f : __builtin_amdgcn_exp2f(st[n][3]);
        } else {
            e0 = __builtin_amdgcn_exp2f(st[n][0]); e1 = __builtin_amdgcn_exp2f(st[n][1]);
            e2 = __builtin_amdgcn_exp2f(st[n][2]); e3 = __builtin_amdgcn_exp2f(st[n][3]);
        }
        l += (e0 + e1) + (e2 + e3);
        *(bf16x4*)&Ptw[lm * PKS + ((n * 4 + quad) ^ ((lm & 7) << 1)) * 4] =
            pk4(e0, e1, e2, e3);
    }

    bf16x8 pf0 = *(const bf16x8*)&Ptw[lm * PKS + kb0];
    bf16x8 pf1 = *(const bf16x8*)&Ptw[lm * PKS + kb1];
    #pragma unroll
    for (int dt = 0; dt < 4; ++dt) {
        bf16x8 vf0 = *(const bf16x8*)&Vs[(dt * 16 + lm) * RS + kb0];
        bf16x8 vf1 = *(const bf16x8*)&Vs[(dt * 16 + lm) * RS + kb1];
        oacc[dt] = mfma16(vf0, pf0, oacc[dt]);
        oacc[dt] = mfma16(vf1, pf1, oacc[dt]);
    }
}

__device__ inline void attn_tile2(
    const bf16x8 (&qfA)[2], const bf16x8 (&qfB)[2],
    f32x4 (&oA)[4], f32x4 (&oB)[4], float& lA, float& lB,
    int qbA, int k0, int w, int lm, int quad,
    const __bf16* Ks, const __bf16* Vs, __bf16* PtA, __bf16* PtB)
{
    const int kb0 = (quad ^ (lm & 7)) * 8;
    const int kb1 = ((quad + 4) ^ (lm & 7)) * 8;
    f32x4 stA[4], stB[4];
    #pragma unroll
    for (int n = 0; n < 4; ++n) {
        stA[n] = (f32x4){0.f, 0.f, 0.f, 0.f};
        stB[n] = (f32x4){0.f, 0.f, 0.f, 0.f};
    }

    #pragma unroll
    for (int n = 0; n < 4; ++n) {
        bf16x8 kf0 = *(const bf16x8*)&Ks[(n * 16 + lm) * RS + kb0];
        bf16x8 kf1 = *(const bf16x8*)&Ks[(n * 16 + lm) * RS + kb1];
        stB[n] = mfma16(kf0, qfB[0], stB[n]);
        stB[n] = mfma16(kf1, qfB[1], stB[n]);
        stA[n] = mfma16(kf0, qfA[0], stA[n]);
        stA[n] = mfma16(kf1, qfA[1], stA[n]);
    }

    #pragma unroll
    for (int n = 0; n < 4; ++n) {
        float e0 = __builtin_amdgcn_exp2f(stB[n][0]);
        float e1 = __builtin_amdgcn_exp2f(stB[n][1]);
        float e2 = __builtin_amdgcn_exp2f(stB[n][2]);
        float e3 = __builtin_amdgcn_exp2f(stB[n][3]);
        lB += (e0 + e1) + (e2 + e3);
        *(bf16x4*)&PtB[lm * PKS + ((n * 4 + quad) ^ ((lm & 7) << 1)) * 4] =
            pk4(e0, e1, e2, e3);
    }

    const int qiA = qbA + w * 16 + lm;
    const bool maskA = (k0 + 63 > qbA + w * 16);
    #pragma unroll
    for (int n = 0; n < 4; ++n) {
        const int kv0 = k0 + n * 16 + quad * 4;
        float e0, e1, e2, e3;
        if (maskA) {
            e0 = (kv0     > qiA) ? 0.f : __builtin_amdgcn_exp2f(stA[n][0]);
            e1 = (kv0 + 1 > qiA) ? 0.f : __builtin_amdgcn_exp2f(stA[n][1]);
            e2 = (kv0 + 2 > qiA) ? 0.f : __builtin_amdgcn_exp2f(stA[n][2]);
            e3 = (kv0 + 3 > qiA) ? 0.f : __builtin_amdgcn_exp2f(stA[n][3]);
        } else {
            e0 = __builtin_amdgcn_exp2f(stA[n][0]); e1 = __builtin_amdgcn_exp2f(stA[n][1]);
            e2 = __builtin_amdgcn_exp2f(stA[n][2]); e3 = __builtin_amdgcn_exp2f(stA[n][3]);
        }
        lA += (e0 + e1) + (e2 + e3);
        *(bf16x4*)&PtA[lm * PKS + ((n * 4 + quad) ^ ((lm & 7) << 1)) * 4] =
            pk4(e0, e1, e2, e3);
    }

    bf16x8 pB0 = *(const bf16x8*)&PtB[lm * PKS + kb0];
    bf16x8 pB1 = *(const bf16x8*)&PtB[lm * PKS + kb1];
    bf16x8 pA0 = *(const bf16x8*)&PtA[lm * PKS + kb0];
    bf16x8 pA1 = *(const bf16x8*)&PtA[lm * PKS + kb1];
    #pragma unroll
    for (int dt = 0; dt < 4; ++dt) {
        bf16x8 vf0 = *(const bf16x8*)&Vs[(dt * 16 + lm) * RS + kb0];
        bf16x8 vf1 = *(const bf16x8*)&Vs[(dt * 16 + lm) * RS + kb1];
        oB[dt] = mfma16(vf0, pB0, oB[dt]);
        oB[dt] = mfma16(vf1, pB1, oB[dt]);
        oA[dt] = mfma16(vf0, pA0, oA[dt]);
        oA[dt] = mfma16(vf1, pA1, oA[dt]);
    }
}

__device__ inline void attn_epilogue(
    f32x4 (&oacc)[4], float l,
    int qbase, int w, int lm, int quad, int b, int h, __bf16* o)
{
    float ls = l;
    ls += __shfl_xor(ls, 16);
    ls += __shfl_xor(ls, 32);
    float rinv = 1.0f / ls;
    const size_t rowbase = (size_t)(b * 2048 + qbase + w * 16 + lm) * 2048 + h * 64;
    #pragma unroll
    for (int dt = 0; dt < 4; ++dt) {
        *(bf16x4*)(o + rowbase + dt * 16 + quad * 4) =
            pk4(oacc[dt][0] * rinv, oacc[dt][1] * rinv,
                oacc[dt][2] * rinv, oacc[dt][3] * rinv);
    }
}

__global__ __launch_bounds__(512, 4) void attn_kernel(
    const __bf16* __restrict__ qkv, const __bf16* __restrict__ vt,
    __bf16* __restrict__ o)
{
    __shared__ __bf16 Ks[2][64 * RS];
    __shared__ __bf16 Vs[2][64 * RS];
    __shared__ __bf16 Pt[8][2][16 * PKS];
    const int tid  = threadIdx.x;
    const int w    = tid >> 6;
    const int lane = tid & 63;
    const int lm   = lane & 15;
    const int quad = lane >> 4;
    const int p = blockIdx.x, h = blockIdx.y, b = blockIdx.z;
    const int kvh = h >> 2;
    const int qbA = p * 128, qbB = (15 - p) * 128;
    const int ntA = 2 * p + 2, ntB = 32 - 2 * p;
    __bf16* PtwB = &Pt[w][0][0];
    __bf16* PtwA = &Pt[w][1][0];

    bf16x8 qfA[2], qfB[2];
    #pragma unroll
    for (int kh = 0; kh < 2; ++kh) {
        qfA[kh] = *(const bf16x8*)(qkv + (size_t)(b * 2048 + qbA + w * 16 + lm) * 3072
                                      + h * 64 + kh * 32 + quad * 8);
        qfB[kh] = *(const bf16x8*)(qkv + (size_t)(b * 2048 + qbB + w * 16 + lm) * 3072
                                      + h * 64 + kh * 32 + quad * 8);
    }

    f32x4 oA[4], oB[4];
    float lA = 0.f, lB = 0.f;
    #pragma unroll
    for (int j = 0; j < 4; ++j) {
        oA[j] = (f32x4){0.f, 0.f, 0.f, 0.f};
        oB[j] = (f32x4){0.f, 0.f, 0.f, 0.f};
    }

    const int srow = tid >> 3;
    const int scg  = (tid & 7) * 8;                          // global col
    const int scl  = (((tid & 7) ^ (srow & 7))) * 8;         // swizzled LDS col
    const __bf16* kbase = qkv + (size_t)(b * 2048) * 3072 + 2048 + kvh * 64;
    const __bf16* vbase = vt  + (size_t)(kvh * 64 + srow) * 4096 + b * 2048;

    int4 kr0, vr0;
    kr0 = *(const int4*)(kbase + (size_t)srow * 3072 + scg);
    vr0 = *(const int4*)(vbase + scg);

    for (int kt = 0; kt < ntB; ++kt) {
        const int c = kt & 1;
        const int k0 = kt * 64;
        *(int4*)&Ks[c][srow * RS + scl] = kr0;
        *(int4*)&Vs[c][srow * RS + scl] = vr0;
        if (kt + 1 < ntB) {
            kr0 = *(const int4*)(kbase + (size_t)(k0 + 64 + srow) * 3072 + scg);
            vr0 = *(const int4*)(vbase + k0 + 64 + scg);
        }
        __syncthreads();
        if (kt < ntA)
            attn_tile2(qfA, qfB, oA, oB, lA, lB, qbA, k0, w, lm, quad,
                       Ks[c], Vs[c], PtwA, PtwB);
        else
            attn_tile(qfB, oB, lB, qbB, k0, w, lm, quad, Ks[c], Vs[c], PtwB);
    }

    attn_epilogue(oA, lA, qbA, w, lm, quad, b, h, o);
    attn_epilogue(oB, lB, qbB, w, lm, quad, b, h, o);
}

// ---------------------------------------------------------------------------
extern "C" void kernel_launch(void* const* d_in, const int* in_sizes, int n_in,
                              void* d_out, int out_size, void* d_ws, size_t ws_size,
                              hipStream_t stream)
{
    const float* x  = (const float*)d_in[0];
    const float* Wq = (const float*)d_in[1];
    const float* Wk = (const float*)d_in[2];
    const float* Wv = (const float*)d_in[3];
    const float* Wo = (const float*)d_in[4];

    const size_t Mi = 1u << 20;
    // d_out (32 MiB fp32) is scratch until the final GEMM writes it.
    char* ob = (char*)d_out;
    __bf16* xb    = (__bf16*)ob;              // 16 MiB  [4096][2048]
    __bf16* wqkvb = (__bf16*)(ob + 16 * Mi);  // 12 MiB  [3072][2048]
    __bf16* vt    = (__bf16*)(ob + 28 * Mi);  //  4 MiB  [512][4096]
    // d_ws (>= 40 MiB, proven)
    char* ws = (char*)d_ws;
    __bf16* qkvc = (__bf16*)ws;               // 24 MiB  [4096][3072]  Q|K (V -> vt)
    __bf16* aws  = (__bf16*)(ws + 24 * Mi);   // 16 MiB  [4096][2048]

    // Wo-bf16 placement: if workspace has 8 MiB spare, convert early in cvt4
    // (saves one launch); else convert after attn into qkvc's dead space.
    const bool early_wo = (ws_size >= 48 * Mi);
    __bf16* wob = early_wo ? (__bf16*)(ws + 40 * Mi) : (__bf16*)ws;

    dim3 blk(256);
    const int cvt_blocks = early_wo ? 18432 : 14336;
    cvt4_kernel<<<cvt_blocks, blk, 0, stream>>>(x, Wq, Wk, Wv, Wo, xb, wqkvb, wob);
    gemm_qkv<<<dim3(16, 16), dim3(512), 0, stream>>>(xb, wqkvb, qkvc, vt, 4096, 3072, 2048);
    attn_kernel<<<dim3(8, 32, 2), dim3(512), 0, stream>>>(qkvc, vt, aws);
    if (!early_wo)
        cvt_kernel<<<4096, blk, 0, stream>>>(Wo, wob, 1048576);
    gemm_o<<<dim3(16, 16), dim3(512), 0, stream>>>(aws, wob, (float*)d_out, 4096, 2048, 2048);
}